// Round 6
// baseline (3806.479 us; speedup 1.0000x reference)
//
#include <hip/hip_runtime.h>
#include <hip/hip_bf16.h>

typedef __hip_bfloat16 bf16;

constexpr int NN = 50000;           // nodes
constexpr int NE = 800000;          // edges (without self loops)
constexpr int NT = NE + NN;         // edges incl self loops
constexpr int NSCB = (NN + 255)/256; // 196 scan blocks

// flag-selected load: f32 storage vs bf16 storage
__device__ __forceinline__ float cvt(const void* p, long long i, int f32){
  return f32 ? ((const float*)p)[i] : __bfloat162float(((const bf16*)p)[i]);
}
__device__ __forceinline__ float4 ld4f(const void* X, size_t idx4, int f32){
  if(f32) return ((const float4*)X)[idx4];
  ushort4 u = ((const ushort4*)X)[idx4];
  float4 r;
  r.x = __uint_as_float((unsigned)u.x << 16);
  r.y = __uint_as_float((unsigned)u.y << 16);
  r.z = __uint_as_float((unsigned)u.z << 16);
  r.w = __uint_as_float((unsigned)u.w << 16);
  return r;
}

// Storage-dtype detector (see R2 notes): flag=1 => f32 storage, 0 => bf16.
__global__ void k_detect(const void* w, int n, int* flag){
  __shared__ int bad;
  if(threadIdx.x == 0) bad = 0;
  __syncthreads();
  const unsigned short* p = (const unsigned short*)w;
  int local = 0;
  for(int i = threadIdx.x; i < n; i += 256){
    int e = (p[i] >> 7) & 0xFF;
    if(e >= 0xC0) local = 1;
  }
  if(local) atomicOr(&bad, 1);
  __syncthreads();
  if(threadIdx.x == 0) *flag = bad;
}

struct SrcPtrs { const void* p[12]; };
__global__ void k_cvtall(SrcPtrs sp, float* Wc, const int* flag){
  const int sz[12]  = {8192,64,4096,64,8192,128,128,128,8192,64,64,32};
  const int off[12] = {0,8192,8256,12352,12416,20608,20736,20864,20992,29184,29248,29312};
  int b = blockIdx.x;
  int f = *flag;
  const void* src = sp.p[b];
  float* dst = Wc + off[b];
  int n = sz[b];
  for(int i = threadIdx.x; i < n; i += 256) dst[i] = cvt(src, i, f);
}

// ---------------- CSR build (dst-bucketed, self-loops included) ----------------
__global__ void k_init_counts(int* __restrict__ counts){
  int i = blockIdx.x*256 + threadIdx.x;
  if(i < NN) counts[i] = 1;          // self loop
}
__global__ void k_count_edges(const int* __restrict__ ei, int* __restrict__ counts){
  int e = blockIdx.x*256 + threadIdx.x;
  if(e < NE) atomicAdd(&counts[ei[NE + e]], 1);
}
__global__ void k_scan1(const int* __restrict__ counts, int* __restrict__ bsum){
  __shared__ int sh[256];
  int i = blockIdx.x*256 + threadIdx.x;
  sh[threadIdx.x] = (i < NN) ? counts[i] : 0;
  __syncthreads();
  for(int off = 128; off; off >>= 1){
    if(threadIdx.x < off) sh[threadIdx.x] += sh[threadIdx.x + off];
    __syncthreads();
  }
  if(threadIdx.x == 0) bsum[blockIdx.x] = sh[0];
}
__global__ void k_scan2(int* __restrict__ bsum){
  __shared__ int sh[2][256];
  int t = threadIdx.x;
  sh[0][t] = (t < NSCB) ? bsum[t] : 0;
  __syncthreads();
  int cur = 0;
  for(int off = 1; off < 256; off <<= 1){
    int nxt = cur^1;
    int v = sh[cur][t];
    if(t >= off) v += sh[cur][t-off];
    sh[nxt][t] = v;
    __syncthreads();
    cur = nxt;
  }
  if(t < NSCB) bsum[t] = (t == 0) ? 0 : sh[cur][t-1];
}
__global__ void k_scan3(const int* __restrict__ counts, const int* __restrict__ bsum,
                        int* __restrict__ rowptr, int* __restrict__ cursor,
                        float* __restrict__ dinv, int* __restrict__ srcidx){
  __shared__ int sh[2][256];
  int t = threadIdx.x;
  int i = blockIdx.x*256 + t;
  int c = (i < NN) ? counts[i] : 0;
  sh[0][t] = c;
  __syncthreads();
  int cur = 0;
  for(int off = 1; off < 256; off <<= 1){
    int nxt = cur^1;
    int v = sh[cur][t];
    if(t >= off) v += sh[cur][t-off];
    sh[nxt][t] = v;
    __syncthreads();
    cur = nxt;
  }
  if(i < NN){
    int excl = bsum[blockIdx.x] + sh[cur][t] - c;
    rowptr[i] = excl;
    srcidx[excl] = i;        // self-loop at row start, no atomic needed
    cursor[i] = excl + 1;    // edges fill after it
    dinv[i] = rsqrtf((float)c);
  }
}
__global__ void k_fill(const int* __restrict__ ei, int* __restrict__ cursor,
                       int* __restrict__ srcidx){
  int e = blockIdx.x*256 + threadIdx.x;
  if(e < NE){
    int dst = ei[NE + e];
    int pos = atomicAdd(&cursor[dst], 1);
    srcidx[pos] = ei[e];
  }
}
// after k_fill, cursor[n] == row end for node n.

// ---------------- dense layers ----------------
// wave = 4 rows x KOUT cols; W in LDS (row-major, stride-1 reads are conflict-free);
// X read as per-wave float4 broadcast loads; optional row prescale by dinv.
template<int KIN, int KOUT, bool SCALE>
__global__ void k_gemm(const float* __restrict__ X, const float* __restrict__ W,
                       const float* __restrict__ dinv, float* __restrict__ C){
  constexpr int NC = KOUT/64;
  __shared__ float Wl[KIN*KOUT];
  for(int i = threadIdx.x; i < KIN*KOUT/4; i += 256)
    ((float4*)Wl)[i] = ((const float4*)W)[i];
  __syncthreads();
  int wid = threadIdx.x >> 6, lane = threadIdx.x & 63;
  int row0 = blockIdx.x*16 + wid*4;
  float acc[4][NC];
#pragma unroll
  for(int r = 0; r < 4; r++)
#pragma unroll
    for(int c = 0; c < NC; c++) acc[r][c] = 0.0f;
  for(int k = 0; k < KIN; k += 4){
    float4 xv[4];
#pragma unroll
    for(int r = 0; r < 4; r++){
      int row = row0 + r;
      xv[r] = (row < NN) ? *(const float4*)(X + (size_t)row*KIN + k)
                         : make_float4(0.f,0.f,0.f,0.f);
    }
#pragma unroll
    for(int kk = 0; kk < 4; kk++){
      float xs[4] = { kk==0?xv[0].x:kk==1?xv[0].y:kk==2?xv[0].z:xv[0].w,
                      kk==0?xv[1].x:kk==1?xv[1].y:kk==2?xv[1].z:xv[1].w,
                      kk==0?xv[2].x:kk==1?xv[2].y:kk==2?xv[2].z:xv[2].w,
                      kk==0?xv[3].x:kk==1?xv[3].y:kk==2?xv[3].z:xv[3].w };
#pragma unroll
      for(int c = 0; c < NC; c++){
        float w = Wl[(k+kk)*KOUT + c*64 + lane];
#pragma unroll
        for(int r = 0; r < 4; r++) acc[r][c] += xs[r]*w;
      }
    }
  }
#pragma unroll
  for(int r = 0; r < 4; r++){
    int row = row0 + r;
    if(row < NN){
      float s = SCALE ? dinv[row] : 1.0f;
#pragma unroll
      for(int c = 0; c < NC; c++)
        C[(size_t)row*KOUT + c*64 + lane] = acc[r][c]*s;
    }
  }
}

// layer-1 variant: X via dtype flag
template<int KIN, int KOUT, bool SCALE>
__global__ void k_gemm_in(const void* __restrict__ X, const float* __restrict__ W,
                          const float* __restrict__ dinv, float* __restrict__ C,
                          const int* __restrict__ flag){
  constexpr int NC = KOUT/64;
  __shared__ float Wl[KIN*KOUT];
  for(int i = threadIdx.x; i < KIN*KOUT/4; i += 256)
    ((float4*)Wl)[i] = ((const float4*)W)[i];
  __syncthreads();
  int f = *flag;
  int wid = threadIdx.x >> 6, lane = threadIdx.x & 63;
  int row0 = blockIdx.x*16 + wid*4;
  float acc[4][NC];
#pragma unroll
  for(int r = 0; r < 4; r++)
#pragma unroll
    for(int c = 0; c < NC; c++) acc[r][c] = 0.0f;
  for(int k = 0; k < KIN; k += 4){
    float4 xv[4];
#pragma unroll
    for(int r = 0; r < 4; r++){
      int row = row0 + r;
      xv[r] = (row < NN) ? ld4f(X, ((size_t)row*KIN + k)>>2, f)
                         : make_float4(0.f,0.f,0.f,0.f);
    }
#pragma unroll
    for(int kk = 0; kk < 4; kk++){
      float xs[4] = { kk==0?xv[0].x:kk==1?xv[0].y:kk==2?xv[0].z:xv[0].w,
                      kk==0?xv[1].x:kk==1?xv[1].y:kk==2?xv[1].z:xv[1].w,
                      kk==0?xv[2].x:kk==1?xv[2].y:kk==2?xv[2].z:xv[2].w,
                      kk==0?xv[3].x:kk==1?xv[3].y:kk==2?xv[3].z:xv[3].w };
#pragma unroll
      for(int c = 0; c < NC; c++){
        float w = Wl[(k+kk)*KOUT + c*64 + lane];
#pragma unroll
        for(int r = 0; r < 4; r++) acc[r][c] += xs[r]*w;
      }
    }
  }
#pragma unroll
  for(int r = 0; r < 4; r++){
    int row = row0 + r;
    if(row < NN){
      float s = SCALE ? dinv[row] : 1.0f;
#pragma unroll
      for(int c = 0; c < NC; c++)
        C[(size_t)row*KOUT + c*64 + lane] = acc[r][c]*s;
    }
  }
}

// per (node, head) attention scores s = <h, a_src>, d = <h, a_dst>
template<int C>
__global__ void k_gat_scores(const float* __restrict__ Hg, const float* __restrict__ asrc,
                             const float* __restrict__ adst, float* __restrict__ sS, float* __restrict__ sD){
  int i = blockIdx.x*256 + threadIdx.x;
  if(i >= NN*2) return;
  int node = i >> 1, h = i & 1;
  const float4* hp = (const float4*)(Hg + (size_t)node*2*C + h*C);
  const float4* as = (const float4*)(asrc + h*C);
  const float4* ad = (const float4*)(adst + h*C);
  float s = 0.0f, d = 0.0f;
#pragma unroll
  for(int c = 0; c < C/4; c++){
    float4 v = hp[c], a = as[c], b = ad[c];
    s += v.x*a.x + v.y*a.y + v.z*a.z + v.w*a.w;
    d += v.x*b.x + v.y*b.y + v.z*b.z + v.w*b.w;
  }
  sS[i] = s; sD[i] = d;
}

// ---------------- gather aggregations (one wave per dst node) ----------------
// GCN: A is prescaled by dinv[src] in GEMM epilogue.
// B[n][l] = relu( dinv[n] * sum_src A'[src][l] + bias[l] )
__global__ void k_gcn_gather(const int* __restrict__ rowptr, const int* __restrict__ rowend,
                             const int* __restrict__ srcidx, const float* __restrict__ dinv,
                             const float* __restrict__ A, const float* __restrict__ bias,
                             float* __restrict__ B){
  int wid = threadIdx.x >> 6, lane = threadIdx.x & 63;
  int n = blockIdx.x*4 + wid;
  if(n >= NN) return;
  int s0 = rowptr[n], ne = rowend[n] - s0;
  float acc = 0.0f;
  for(int base = 0; base < ne; base += 64){
    int my = base + lane;
    int src = (my < ne) ? srcidx[s0 + my] : 0;
    int cnt = min(64, ne - base);
#pragma unroll 4
    for(int j = 0; j < cnt; j++){
      int sb = __shfl(src, j);
      acc += A[(size_t)sb*64 + lane];
    }
  }
  float v = acc*dinv[n] + bias[lane];
  B[(size_t)n*64 + lane] = fmaxf(v, 0.0f);
}

// GAT1 (heads=2, C=64, concat): segment-softmax + aggregate + bias + relu.
// Phase B: per-edge scalars computed once per lane, shfl-broadcast to the wave.
__global__ void k_gat1_gather(const int* __restrict__ rowptr, const int* __restrict__ rowend,
                              const int* __restrict__ srcidx, const float* __restrict__ sS,
                              const float* __restrict__ sD, const float* __restrict__ Hg,
                              const float* __restrict__ bias, float* __restrict__ B){
  int wid = threadIdx.x >> 6, lane = threadIdx.x & 63;
  int n = blockIdx.x*4 + wid;
  if(n >= NN) return;
  int s0 = rowptr[n], ne = rowend[n] - s0;
  float d0 = sD[n*2], d1 = sD[n*2+1];
  // phase A: per-lane online (m,z) per head over strided edges
  float m0 = -1e30f, z0 = 0.0f, m1 = -1e30f, z1 = 0.0f;
  for(int i = lane; i < ne; i += 64){
    int src = srcidx[s0 + i];
    float2 sv = *(const float2*)(sS + src*2);
    float e0 = sv.x + d0; e0 = e0 > 0.0f ? e0 : 0.2f*e0;
    float e1 = sv.y + d1; e1 = e1 > 0.0f ? e1 : 0.2f*e1;
    if(e0 > m0){ z0 *= __expf(m0 - e0); m0 = e0; }
    z0 += __expf(e0 - m0);
    if(e1 > m1){ z1 *= __expf(m1 - e1); m1 = e1; }
    z1 += __expf(e1 - m1);
  }
  for(int off = 32; off; off >>= 1){
    float mo = __shfl_xor(m0, off), zo = __shfl_xor(z0, off);
    float mn = fmaxf(m0, mo);
    z0 = z0*__expf(m0 - mn) + zo*__expf(mo - mn); m0 = mn;
    mo = __shfl_xor(m1, off); zo = __shfl_xor(z1, off);
    mn = fmaxf(m1, mo);
    z1 = z1*__expf(m1 - mn) + zo*__expf(mo - mn); m1 = mn;
  }
  // phase B: chunk of 64 edges; lane j computes (src, w0, w1), wave broadcasts
  float acc0 = 0.0f, acc1 = 0.0f;
  for(int base = 0; base < ne; base += 64){
    int my = base + lane;
    int src = 0; float w0 = 0.0f, w1 = 0.0f;
    if(my < ne){
      src = srcidx[s0 + my];
      float2 sv = *(const float2*)(sS + src*2);
      float e0 = sv.x + d0; e0 = e0 > 0.0f ? e0 : 0.2f*e0;
      float e1 = sv.y + d1; e1 = e1 > 0.0f ? e1 : 0.2f*e1;
      w0 = __expf(e0 - m0); w1 = __expf(e1 - m1);
    }
    int cnt = min(64, ne - base);
#pragma unroll 4
    for(int j = 0; j < cnt; j++){
      int sb = __shfl(src, j);
      float a0 = __shfl(w0, j), a1 = __shfl(w1, j);
      const float* hp = Hg + (size_t)sb*128;
      acc0 += hp[lane]      * a0;
      acc1 += hp[64 + lane] * a1;
    }
  }
  float o0 = acc0/(z0 + 1e-16f) + bias[lane];
  float o1 = acc1/(z1 + 1e-16f) + bias[64 + lane];
  B[(size_t)n*128 + lane]      = fmaxf(o0, 0.0f);
  B[(size_t)n*128 + 64 + lane] = fmaxf(o1, 0.0f);
}

// GAT2 (heads=2, C=32, mean) + bias + log_softmax + dtype-flagged output
__global__ void k_gat2_final(const int* __restrict__ rowptr, const int* __restrict__ rowend,
                             const int* __restrict__ srcidx, const float* __restrict__ sS,
                             const float* __restrict__ sD, const float* __restrict__ Hg,
                             const float* __restrict__ bias, void* __restrict__ out,
                             const int* __restrict__ flag){
  int wid = threadIdx.x >> 6, lane = threadIdx.x & 63;
  int n = blockIdx.x*4 + wid;
  if(n >= NN) return;
  int s0 = rowptr[n], ne = rowend[n] - s0;
  float d0 = sD[n*2], d1 = sD[n*2+1];
  float m0 = -1e30f, z0 = 0.0f, m1 = -1e30f, z1 = 0.0f;
  for(int i = lane; i < ne; i += 64){
    int src = srcidx[s0 + i];
    float2 sv = *(const float2*)(sS + src*2);
    float e0 = sv.x + d0; e0 = e0 > 0.0f ? e0 : 0.2f*e0;
    float e1 = sv.y + d1; e1 = e1 > 0.0f ? e1 : 0.2f*e1;
    if(e0 > m0){ z0 *= __expf(m0 - e0); m0 = e0; }
    z0 += __expf(e0 - m0);
    if(e1 > m1){ z1 *= __expf(m1 - e1); m1 = e1; }
    z1 += __expf(e1 - m1);
  }
  for(int off = 32; off; off >>= 1){
    float mo = __shfl_xor(m0, off), zo = __shfl_xor(z0, off);
    float mn = fmaxf(m0, mo);
    z0 = z0*__expf(m0 - mn) + zo*__expf(mo - mn); m0 = mn;
    mo = __shfl_xor(m1, off); zo = __shfl_xor(z1, off);
    mn = fmaxf(m1, mo);
    z1 = z1*__expf(m1 - mn) + zo*__expf(mo - mn); m1 = mn;
  }
  float acc = 0.0f;
  for(int base = 0; base < ne; base += 64){
    int my = base + lane;
    int src = 0; float w0 = 0.0f, w1 = 0.0f;
    if(my < ne){
      src = srcidx[s0 + my];
      float2 sv = *(const float2*)(sS + src*2);
      float e0 = sv.x + d0; e0 = e0 > 0.0f ? e0 : 0.2f*e0;
      float e1 = sv.y + d1; e1 = e1 > 0.0f ? e1 : 0.2f*e1;
      w0 = __expf(e0 - m0); w1 = __expf(e1 - m1);
    }
    int cnt = min(64, ne - base);
#pragma unroll 4
    for(int j = 0; j < cnt; j++){
      int sb = __shfl(src, j);
      float a0 = __shfl(w0, j), a1 = __shfl(w1, j);
      float wb = (lane < 32) ? a0 : a1;        // head = lane>>5 (C=32 concat layout)
      acc += Hg[(size_t)sb*64 + lane] * wb;
    }
  }
  float zh = (lane < 32) ? z0 : z1;
  float o = acc/(zh + 1e-16f);
  float o2 = __shfl_down(o, 32);               // lane<32 gets head-1 partner
  o = 0.5f*(o + o2) + ((lane < 32) ? bias[lane] : 0.0f);
  float mx = o;
  for(int off = 16; off; off >>= 1) mx = fmaxf(mx, __shfl_xor(mx, off, 32));
  float s = __expf(o - mx);
  for(int off = 16; off; off >>= 1) s += __shfl_xor(s, off, 32);
  float r = o - (mx + __logf(s));
  if(lane < 32){
    if(*flag) ((float*)out)[(size_t)n*32 + lane] = r;
    else      ((bf16*)out)[(size_t)n*32 + lane] = __float2bfloat16(r);
  }
}

extern "C" void kernel_launch(void* const* d_in, const int* in_sizes, int n_in,
                              void* d_out, int out_size, void* d_ws, size_t ws_size,
                              hipStream_t stream) {
  const void* x   = d_in[0];
  const int*  ei  = (const int*)d_in[1];

  // workspace layout:
  // A[NN*128] f32 | B[NN*128] f32 | dinv[NN] | sS[2NN] | sD[2NN] |
  // rowptr[NN] | cursor[NN] | counts[NN] | bsum[256] | srcidx[NT] | Wc[29344] | flag
  float* A    = (float*)d_ws;
  float* B    = A + (size_t)NN*128;
  float* dinv = B + (size_t)NN*128;
  float* sS   = dinv + NN;
  float* sD   = sS + 2*NN;
  int* rowptr = (int*)(sD + 2*NN);
  int* cursor = rowptr + NN;
  int* counts = cursor + NN;
  int* bsum   = counts + NN;
  int* srcidx = bsum + 256;
  float* Wc   = (float*)(srcidx + NT);
  int*  flag  = (int*)(Wc + 29344);

  const float* W1c  = Wc;
  const float* b1c  = Wc + 8192;
  const float* W2c  = Wc + 8256;
  const float* b2c  = Wc + 12352;
  const float* Wg1c = Wc + 12416;
  const float* as1c = Wc + 20608;
  const float* ad1c = Wc + 20736;
  const float* bg1c = Wc + 20864;
  const float* Wg2c = Wc + 20992;
  const float* as2c = Wc + 29184;
  const float* ad2c = Wc + 29248;
  const float* bg2c = Wc + 29312;

  auto nb = [](long long t){ return dim3((unsigned)((t + 255)/256)); };
  dim3 gnodes((NN + 3)/4);      // 4 waves/block, 1 wave per node
  dim3 ggemm((NN + 15)/16);     // 16 rows/block (4 waves x 4 rows)

  // dtype detect + weight conversion
  k_detect<<<1, 256, 0, stream>>>(d_in[2], 8192, flag);
  SrcPtrs sp;
  for(int i = 0; i < 12; i++) sp.p[i] = d_in[2 + i];
  k_cvtall<<<12, 256, 0, stream>>>(sp, Wc, flag);

  // CSR build (shared by all 4 aggregations) — 3-phase parallel scan
  k_init_counts<<<nb(NN), 256, 0, stream>>>(counts);
  k_count_edges<<<nb(NE), 256, 0, stream>>>(ei, counts);
  k_scan1<<<NSCB, 256, 0, stream>>>(counts, bsum);
  k_scan2<<<1, 256, 0, stream>>>(bsum);
  k_scan3<<<NSCB, 256, 0, stream>>>(counts, bsum, rowptr, cursor, dinv, srcidx);
  k_fill<<<nb(NE), 256, 0, stream>>>(ei, cursor, srcidx);
  // after k_fill: cursor[n] == row end

  // ---- GCN1 ----  (GEMM prescales rows by dinv)
  k_gemm_in<128,64,true><<<ggemm, 256, 0, stream>>>(x, W1c, dinv, A, flag);
  k_gcn_gather<<<gnodes, 256, 0, stream>>>(rowptr, cursor, srcidx, dinv, A, b1c, B);

  // ---- GCN2 ----
  k_gemm<64,64,true><<<ggemm, 256, 0, stream>>>(B, W2c, dinv, A);
  k_gcn_gather<<<gnodes, 256, 0, stream>>>(rowptr, cursor, srcidx, dinv, A, b2c, B);

  // ---- GAT1: heads=2, C=64, concat ----
  k_gemm<64,128,false><<<ggemm, 256, 0, stream>>>(B, Wg1c, dinv, A);
  k_gat_scores<64><<<nb((long long)NN*2), 256, 0, stream>>>(A, as1c, ad1c, sS, sD);
  k_gat1_gather<<<gnodes, 256, 0, stream>>>(rowptr, cursor, srcidx, sS, sD, A, bg1c, B);

  // ---- GAT2: heads=2, C=32, mean + log_softmax ----
  k_gemm<128,64,false><<<ggemm, 256, 0, stream>>>(B, Wg2c, dinv, A);
  k_gat_scores<32><<<nb((long long)NN*2), 256, 0, stream>>>(A, as2c, ad2c, sS, sD);
  k_gat2_final<<<gnodes, 256, 0, stream>>>(rowptr, cursor, srcidx, sS, sD, A, bg2c, d_out, flag);
}

// Round 7
// 656.973 us; speedup vs baseline: 5.7940x; 5.7940x over previous
//
#include <hip/hip_runtime.h>
#include <hip/hip_bf16.h>

typedef __hip_bfloat16 bf16;

constexpr int NN = 50000;           // nodes
constexpr int NE = 800000;          // edges (without self loops)
constexpr int NT = NE + NN;         // edges incl self loops
constexpr int NSCB = (NN + 255)/256; // 196 scan blocks

// flag-selected load: f32 storage vs bf16 storage
__device__ __forceinline__ float cvt(const void* p, long long i, int f32){
  return f32 ? ((const float*)p)[i] : __bfloat162float(((const bf16*)p)[i]);
}

// Storage-dtype detector (see R2 notes): flag=1 => f32 storage, 0 => bf16.
__global__ void k_detect(const void* w, int n, int* flag){
  __shared__ int bad;
  if(threadIdx.x == 0) bad = 0;
  __syncthreads();
  const unsigned short* p = (const unsigned short*)w;
  int local = 0;
  for(int i = threadIdx.x; i < n; i += 256){
    int e = (p[i] >> 7) & 0xFF;
    if(e >= 0xC0) local = 1;
  }
  if(local) atomicOr(&bad, 1);
  __syncthreads();
  if(threadIdx.x == 0) *flag = bad;
}

struct SrcPtrs { const void* p[12]; };
__global__ void k_cvtall(SrcPtrs sp, float* Wc, const int* flag){
  const int sz[12]  = {8192,64,4096,64,8192,128,128,128,8192,64,64,32};
  const int off[12] = {0,8192,8256,12352,12416,20608,20736,20864,20992,29184,29248,29312};
  int b = blockIdx.x;
  int f = *flag;
  const void* src = sp.p[b];
  float* dst = Wc + off[b];
  int n = sz[b];
  for(int i = threadIdx.x; i < n; i += 256) dst[i] = cvt(src, i, f);
}

// ---------------- CSR build (dst-bucketed, self-loops included) ----------------
__global__ void k_init_counts(int* __restrict__ counts){
  int i = blockIdx.x*256 + threadIdx.x;
  if(i < NN) counts[i] = 1;          // self loop
}
__global__ void k_count_edges(const int* __restrict__ ei, int* __restrict__ counts){
  int e = blockIdx.x*256 + threadIdx.x;
  if(e < NE) atomicAdd(&counts[ei[NE + e]], 1);
}
__global__ void k_scan1(const int* __restrict__ counts, int* __restrict__ bsum){
  __shared__ int sh[256];
  int i = blockIdx.x*256 + threadIdx.x;
  sh[threadIdx.x] = (i < NN) ? counts[i] : 0;
  __syncthreads();
  for(int off = 128; off; off >>= 1){
    if(threadIdx.x < off) sh[threadIdx.x] += sh[threadIdx.x + off];
    __syncthreads();
  }
  if(threadIdx.x == 0) bsum[blockIdx.x] = sh[0];
}
__global__ void k_scan2(int* __restrict__ bsum){
  __shared__ int sh[2][256];
  int t = threadIdx.x;
  sh[0][t] = (t < NSCB) ? bsum[t] : 0;
  __syncthreads();
  int cur = 0;
  for(int off = 1; off < 256; off <<= 1){
    int nxt = cur^1;
    int v = sh[cur][t];
    if(t >= off) v += sh[cur][t-off];
    sh[nxt][t] = v;
    __syncthreads();
    cur = nxt;
  }
  if(t < NSCB) bsum[t] = (t == 0) ? 0 : sh[cur][t-1];
}
__global__ void k_scan3(const int* __restrict__ counts, const int* __restrict__ bsum,
                        int* __restrict__ rowptr, int* __restrict__ cursor,
                        float* __restrict__ dinv, int* __restrict__ srcidx){
  __shared__ int sh[2][256];
  int t = threadIdx.x;
  int i = blockIdx.x*256 + t;
  int c = (i < NN) ? counts[i] : 0;
  sh[0][t] = c;
  __syncthreads();
  int cur = 0;
  for(int off = 1; off < 256; off <<= 1){
    int nxt = cur^1;
    int v = sh[cur][t];
    if(t >= off) v += sh[cur][t-off];
    sh[nxt][t] = v;
    __syncthreads();
    cur = nxt;
  }
  if(i < NN){
    int excl = bsum[blockIdx.x] + sh[cur][t] - c;
    rowptr[i] = excl;
    srcidx[excl] = i;        // self-loop at row start, no atomic needed
    cursor[i] = excl + 1;    // edges fill after it
    dinv[i] = rsqrtf((float)c);
  }
}
__global__ void k_fill(const int* __restrict__ ei, int* __restrict__ cursor,
                       int* __restrict__ srcidx){
  int e = blockIdx.x*256 + threadIdx.x;
  if(e < NE){
    int dst = ei[NE + e];
    int pos = atomicAdd(&cursor[dst], 1);
    srcidx[pos] = ei[e];
  }
}
// after k_fill, cursor[n] == row end for node n.

// ---------------- dense layers (R5-proven structure: no private arrays) ----------------
template<int KIN, int KOUT, bool SCALE>
__global__ void k_gemm_f(const float* __restrict__ X, const float* __restrict__ W,
                         const float* __restrict__ dinv, float* __restrict__ C){
  constexpr int R = 256 / KOUT;            // rows per block
  __shared__ float Wl[KIN * KOUT];
  __shared__ float Xl[R][KIN];
  int tid = threadIdx.y * KOUT + threadIdx.x;
  for(int i = tid; i < KIN*KOUT; i += 256) Wl[i] = W[i];
  int row0 = blockIdx.x * R;
  for(int i = tid; i < R*KIN; i += 256){
    int r = i / KIN, k = i - r*KIN;
    int rr = row0 + r;
    Xl[r][k] = (rr < NN) ? X[(size_t)rr*KIN + k] : 0.0f;
  }
  __syncthreads();
  int row = row0 + threadIdx.y;
  if(row >= NN) return;
  float acc = 0.0f;
#pragma unroll
  for(int k = 0; k < KIN; k++) acc += Xl[threadIdx.y][k] * Wl[k*KOUT + threadIdx.x];
  float s = SCALE ? dinv[row] : 1.0f;
  C[(size_t)row*KOUT + threadIdx.x] = acc * s;
}

template<int KIN, int KOUT, bool SCALE>
__global__ void k_gemm_in(const void* __restrict__ X, const float* __restrict__ W,
                          const float* __restrict__ dinv, float* __restrict__ C,
                          const int* __restrict__ flag){
  constexpr int R = 256 / KOUT;
  __shared__ float Wl[KIN * KOUT];
  __shared__ float Xl[R][KIN];
  int tid = threadIdx.y * KOUT + threadIdx.x;
  int f = *flag;
  for(int i = tid; i < KIN*KOUT; i += 256) Wl[i] = W[i];
  int row0 = blockIdx.x * R;
  for(int i = tid; i < R*KIN; i += 256){
    int r = i / KIN, k = i - r*KIN;
    int rr = row0 + r;
    Xl[r][k] = (rr < NN) ? cvt(X, (long long)rr*KIN + k, f) : 0.0f;
  }
  __syncthreads();
  int row = row0 + threadIdx.y;
  if(row >= NN) return;
  float acc = 0.0f;
#pragma unroll
  for(int k = 0; k < KIN; k++) acc += Xl[threadIdx.y][k] * Wl[k*KOUT + threadIdx.x];
  float s = SCALE ? dinv[row] : 1.0f;
  C[(size_t)row*KOUT + threadIdx.x] = acc * s;
}

// per (node, head) attention scores s = <h, a_src>, d = <h, a_dst>
template<int C>
__global__ void k_gat_scores(const float* __restrict__ Hg, const float* __restrict__ asrc,
                             const float* __restrict__ adst, float* __restrict__ sS, float* __restrict__ sD){
  int i = blockIdx.x*256 + threadIdx.x;
  if(i >= NN*2) return;
  int node = i >> 1, h = i & 1;
  const float4* hp = (const float4*)(Hg + (size_t)node*2*C + h*C);
  const float4* as = (const float4*)(asrc + h*C);
  const float4* ad = (const float4*)(adst + h*C);
  float s = 0.0f, d = 0.0f;
#pragma unroll
  for(int c = 0; c < C/4; c++){
    float4 v = hp[c], a = as[c], b = ad[c];
    s += v.x*a.x + v.y*a.y + v.z*a.z + v.w*a.w;
    d += v.x*b.x + v.y*b.y + v.z*b.z + v.w*b.w;
  }
  sS[i] = s; sD[i] = d;
}

// ---------------- gather aggregations (one wave per dst node) ----------------
// GCN: A is prescaled by dinv[src] in GEMM epilogue.
// B[n][l] = relu( dinv[n] * sum_src A'[src][l] + bias[l] )
__global__ void k_gcn_gather(const int* __restrict__ rowptr, const int* __restrict__ rowend,
                             const int* __restrict__ srcidx, const float* __restrict__ dinv,
                             const float* __restrict__ A, const float* __restrict__ bias,
                             float* __restrict__ B){
  int wid = threadIdx.x >> 6, lane = threadIdx.x & 63;
  int n = blockIdx.x*4 + wid;
  if(n >= NN) return;
  int s0 = rowptr[n], ne = rowend[n] - s0;
  float acc = 0.0f;
  for(int base = 0; base < ne; base += 64){
    int my = base + lane;
    int src = (my < ne) ? srcidx[s0 + my] : 0;
    int cnt = min(64, ne - base);
#pragma unroll 4
    for(int j = 0; j < cnt; j++){
      int sb = __shfl(src, j);
      acc += A[(size_t)sb*64 + lane];
    }
  }
  float v = acc*dinv[n] + bias[lane];
  B[(size_t)n*64 + lane] = fmaxf(v, 0.0f);
}

// GAT1 (heads=2, C=64, concat): segment-softmax + aggregate + bias + relu.
// Phase B: per-edge scalars computed once per lane, shfl-broadcast to the wave.
__global__ void k_gat1_gather(const int* __restrict__ rowptr, const int* __restrict__ rowend,
                              const int* __restrict__ srcidx, const float* __restrict__ sS,
                              const float* __restrict__ sD, const float* __restrict__ Hg,
                              const float* __restrict__ bias, float* __restrict__ B){
  int wid = threadIdx.x >> 6, lane = threadIdx.x & 63;
  int n = blockIdx.x*4 + wid;
  if(n >= NN) return;
  int s0 = rowptr[n], ne = rowend[n] - s0;
  float d0 = sD[n*2], d1 = sD[n*2+1];
  // phase A: per-lane online (m,z) per head over strided edges
  float m0 = -1e30f, z0 = 0.0f, m1 = -1e30f, z1 = 0.0f;
  for(int i = lane; i < ne; i += 64){
    int src = srcidx[s0 + i];
    float2 sv = *(const float2*)(sS + src*2);
    float e0 = sv.x + d0; e0 = e0 > 0.0f ? e0 : 0.2f*e0;
    float e1 = sv.y + d1; e1 = e1 > 0.0f ? e1 : 0.2f*e1;
    if(e0 > m0){ z0 *= __expf(m0 - e0); m0 = e0; }
    z0 += __expf(e0 - m0);
    if(e1 > m1){ z1 *= __expf(m1 - e1); m1 = e1; }
    z1 += __expf(e1 - m1);
  }
  for(int off = 32; off; off >>= 1){
    float mo = __shfl_xor(m0, off), zo = __shfl_xor(z0, off);
    float mn = fmaxf(m0, mo);
    z0 = z0*__expf(m0 - mn) + zo*__expf(mo - mn); m0 = mn;
    mo = __shfl_xor(m1, off); zo = __shfl_xor(z1, off);
    mn = fmaxf(m1, mo);
    z1 = z1*__expf(m1 - mn) + zo*__expf(mo - mn); m1 = mn;
  }
  // phase B: chunk of 64 edges; lane j computes (src, w0, w1), wave broadcasts
  float acc0 = 0.0f, acc1 = 0.0f;
  for(int base = 0; base < ne; base += 64){
    int my = base + lane;
    int src = 0; float w0 = 0.0f, w1 = 0.0f;
    if(my < ne){
      src = srcidx[s0 + my];
      float2 sv = *(const float2*)(sS + src*2);
      float e0 = sv.x + d0; e0 = e0 > 0.0f ? e0 : 0.2f*e0;
      float e1 = sv.y + d1; e1 = e1 > 0.0f ? e1 : 0.2f*e1;
      w0 = __expf(e0 - m0); w1 = __expf(e1 - m1);
    }
    int cnt = min(64, ne - base);
#pragma unroll 4
    for(int j = 0; j < cnt; j++){
      int sb = __shfl(src, j);
      float a0 = __shfl(w0, j), a1 = __shfl(w1, j);
      const float* hp = Hg + (size_t)sb*128;
      acc0 += hp[lane]      * a0;
      acc1 += hp[64 + lane] * a1;
    }
  }
  float o0 = acc0/(z0 + 1e-16f) + bias[lane];
  float o1 = acc1/(z1 + 1e-16f) + bias[64 + lane];
  B[(size_t)n*128 + lane]      = fmaxf(o0, 0.0f);
  B[(size_t)n*128 + 64 + lane] = fmaxf(o1, 0.0f);
}

// GAT2 (heads=2, C=32, mean) + bias + log_softmax + dtype-flagged output
__global__ void k_gat2_final(const int* __restrict__ rowptr, const int* __restrict__ rowend,
                             const int* __restrict__ srcidx, const float* __restrict__ sS,
                             const float* __restrict__ sD, const float* __restrict__ Hg,
                             const float* __restrict__ bias, void* __restrict__ out,
                             const int* __restrict__ flag){
  int wid = threadIdx.x >> 6, lane = threadIdx.x & 63;
  int n = blockIdx.x*4 + wid;
  if(n >= NN) return;
  int s0 = rowptr[n], ne = rowend[n] - s0;
  float d0 = sD[n*2], d1 = sD[n*2+1];
  float m0 = -1e30f, z0 = 0.0f, m1 = -1e30f, z1 = 0.0f;
  for(int i = lane; i < ne; i += 64){
    int src = srcidx[s0 + i];
    float2 sv = *(const float2*)(sS + src*2);
    float e0 = sv.x + d0; e0 = e0 > 0.0f ? e0 : 0.2f*e0;
    float e1 = sv.y + d1; e1 = e1 > 0.0f ? e1 : 0.2f*e1;
    if(e0 > m0){ z0 *= __expf(m0 - e0); m0 = e0; }
    z0 += __expf(e0 - m0);
    if(e1 > m1){ z1 *= __expf(m1 - e1); m1 = e1; }
    z1 += __expf(e1 - m1);
  }
  for(int off = 32; off; off >>= 1){
    float mo = __shfl_xor(m0, off), zo = __shfl_xor(z0, off);
    float mn = fmaxf(m0, mo);
    z0 = z0*__expf(m0 - mn) + zo*__expf(mo - mn); m0 = mn;
    mo = __shfl_xor(m1, off); zo = __shfl_xor(z1, off);
    mn = fmaxf(m1, mo);
    z1 = z1*__expf(m1 - mn) + zo*__expf(mo - mn); m1 = mn;
  }
  float acc = 0.0f;
  for(int base = 0; base < ne; base += 64){
    int my = base + lane;
    int src = 0; float w0 = 0.0f, w1 = 0.0f;
    if(my < ne){
      src = srcidx[s0 + my];
      float2 sv = *(const float2*)(sS + src*2);
      float e0 = sv.x + d0; e0 = e0 > 0.0f ? e0 : 0.2f*e0;
      float e1 = sv.y + d1; e1 = e1 > 0.0f ? e1 : 0.2f*e1;
      w0 = __expf(e0 - m0); w1 = __expf(e1 - m1);
    }
    int cnt = min(64, ne - base);
#pragma unroll 4
    for(int j = 0; j < cnt; j++){
      int sb = __shfl(src, j);
      float a0 = __shfl(w0, j), a1 = __shfl(w1, j);
      float wb = (lane < 32) ? a0 : a1;        // head = lane>>5 (C=32 concat layout)
      acc += Hg[(size_t)sb*64 + lane] * wb;
    }
  }
  float zh = (lane < 32) ? z0 : z1;
  float o = acc/(zh + 1e-16f);
  float o2 = __shfl_down(o, 32);               // lane<32 gets head-1 partner
  o = 0.5f*(o + o2) + ((lane < 32) ? bias[lane] : 0.0f);
  float mx = o;
  for(int off = 16; off; off >>= 1) mx = fmaxf(mx, __shfl_xor(mx, off, 32));
  float s = __expf(o - mx);
  for(int off = 16; off; off >>= 1) s += __shfl_xor(s, off, 32);
  float r = o - (mx + __logf(s));
  if(lane < 32){
    if(*flag) ((float*)out)[(size_t)n*32 + lane] = r;
    else      ((bf16*)out)[(size_t)n*32 + lane] = __float2bfloat16(r);
  }
}

extern "C" void kernel_launch(void* const* d_in, const int* in_sizes, int n_in,
                              void* d_out, int out_size, void* d_ws, size_t ws_size,
                              hipStream_t stream) {
  const void* x   = d_in[0];
  const int*  ei  = (const int*)d_in[1];

  // workspace layout:
  // A[NN*128] f32 | B[NN*128] f32 | dinv[NN] | sS[2NN] | sD[2NN] |
  // rowptr[NN] | cursor[NN] | counts[NN] | bsum[256] | srcidx[NT] | Wc[29344] | flag
  float* A    = (float*)d_ws;
  float* B    = A + (size_t)NN*128;
  float* dinv = B + (size_t)NN*128;
  float* sS   = dinv + NN;
  float* sD   = sS + 2*NN;
  int* rowptr = (int*)(sD + 2*NN);
  int* cursor = rowptr + NN;
  int* counts = cursor + NN;
  int* bsum   = counts + NN;
  int* srcidx = bsum + 256;
  float* Wc   = (float*)(srcidx + NT);
  int*  flag  = (int*)(Wc + 29344);

  const float* W1c  = Wc;
  const float* b1c  = Wc + 8192;
  const float* W2c  = Wc + 8256;
  const float* b2c  = Wc + 12352;
  const float* Wg1c = Wc + 12416;
  const float* as1c = Wc + 20608;
  const float* ad1c = Wc + 20736;
  const float* bg1c = Wc + 20864;
  const float* Wg2c = Wc + 20992;
  const float* as2c = Wc + 29184;
  const float* ad2c = Wc + 29248;
  const float* bg2c = Wc + 29312;

  auto nb = [](long long t){ return dim3((unsigned)((t + 255)/256)); };
  dim3 gnodes((NN + 3)/4);      // 4 waves/block, 1 wave per node

  // dtype detect + weight conversion
  k_detect<<<1, 256, 0, stream>>>(d_in[2], 8192, flag);
  SrcPtrs sp;
  for(int i = 0; i < 12; i++) sp.p[i] = d_in[2 + i];
  k_cvtall<<<12, 256, 0, stream>>>(sp, Wc, flag);

  // CSR build (shared by all 4 aggregations) — 3-phase parallel scan
  k_init_counts<<<nb(NN), 256, 0, stream>>>(counts);
  k_count_edges<<<nb(NE), 256, 0, stream>>>(ei, counts);
  k_scan1<<<NSCB, 256, 0, stream>>>(counts, bsum);
  k_scan2<<<1, 256, 0, stream>>>(bsum);
  k_scan3<<<NSCB, 256, 0, stream>>>(counts, bsum, rowptr, cursor, dinv, srcidx);
  k_fill<<<nb(NE), 256, 0, stream>>>(ei, cursor, srcidx);
  // after k_fill: cursor[n] == row end

  // ---- GCN1 ----  (GEMM prescales rows by dinv)
  k_gemm_in<128,64,true><<<dim3((NN+3)/4), dim3(64,4), 0, stream>>>(x, W1c, dinv, A, flag);
  k_gcn_gather<<<gnodes, 256, 0, stream>>>(rowptr, cursor, srcidx, dinv, A, b1c, B);

  // ---- GCN2 ----
  k_gemm_f<64,64,true><<<dim3((NN+3)/4), dim3(64,4), 0, stream>>>(B, W2c, dinv, A);
  k_gcn_gather<<<gnodes, 256, 0, stream>>>(rowptr, cursor, srcidx, dinv, A, b2c, B);

  // ---- GAT1: heads=2, C=64, concat ----
  k_gemm_f<64,128,false><<<dim3((NN+1)/2), dim3(128,2), 0, stream>>>(B, Wg1c, dinv, A);
  k_gat_scores<64><<<nb((long long)NN*2), 256, 0, stream>>>(A, as1c, ad1c, sS, sD);
  k_gat1_gather<<<gnodes, 256, 0, stream>>>(rowptr, cursor, srcidx, sS, sD, A, bg1c, B);

  // ---- GAT2: heads=2, C=32, mean + log_softmax ----
  k_gemm_f<128,64,false><<<dim3((NN+3)/4), dim3(64,4), 0, stream>>>(B, Wg2c, dinv, A);
  k_gat_scores<32><<<nb((long long)NN*2), 256, 0, stream>>>(A, as2c, ad2c, sS, sD);
  k_gat2_final<<<gnodes, 256, 0, stream>>>(rowptr, cursor, srcidx, sS, sD, A, bg2c, d_out, flag);
}

// Round 8
// 555.959 us; speedup vs baseline: 6.8467x; 1.1817x over previous
//
#include <hip/hip_runtime.h>
#include <hip/hip_bf16.h>

typedef __hip_bfloat16 bf16;

constexpr int NN = 50000;           // nodes
constexpr int NE = 800000;          // edges (without self loops)
constexpr int NT = NE + NN;         // edges incl self loops
constexpr int NSCB = (NN + 255)/256; // 196 scan blocks

// flag-selected load: f32 storage vs bf16 storage
__device__ __forceinline__ float cvt(const void* p, long long i, int f32){
  return f32 ? ((const float*)p)[i] : __bfloat162float(((const bf16*)p)[i]);
}
// bf16 <-> f32 (RNE pack; values are finite/well-scaled here)
__device__ __forceinline__ unsigned short f2bf(float f){
  unsigned u = __float_as_uint(f);
  u += 0x7fffu + ((u >> 16) & 1);
  return (unsigned short)(u >> 16);
}
__device__ __forceinline__ float bf2f(unsigned short u){
  return __uint_as_float((unsigned)u << 16);
}

// Storage-dtype detector (see R2 notes): flag=1 => f32 storage, 0 => bf16.
__global__ void k_detect(const void* w, int n, int* flag){
  __shared__ int bad;
  if(threadIdx.x == 0) bad = 0;
  __syncthreads();
  const unsigned short* p = (const unsigned short*)w;
  int local = 0;
  for(int i = threadIdx.x; i < n; i += 256){
    int e = (p[i] >> 7) & 0xFF;
    if(e >= 0xC0) local = 1;
  }
  if(local) atomicOr(&bad, 1);
  __syncthreads();
  if(threadIdx.x == 0) *flag = bad;
}

struct SrcPtrs { const void* p[12]; };
__global__ void k_cvtall(SrcPtrs sp, float* Wc, const int* flag){
  const int sz[12]  = {8192,64,4096,64,8192,128,128,128,8192,64,64,32};
  const int off[12] = {0,8192,8256,12352,12416,20608,20736,20864,20992,29184,29248,29312};
  int b = blockIdx.x;
  int f = *flag;
  const void* src = sp.p[b];
  float* dst = Wc + off[b];
  int n = sz[b];
  for(int i = threadIdx.x; i < n; i += 256) dst[i] = cvt(src, i, f);
}

// ---------------- CSR build (dst-bucketed, self-loops included) ----------------
__global__ void k_init_counts(int* __restrict__ counts){
  int i = blockIdx.x*256 + threadIdx.x;
  if(i < NN) counts[i] = 1;          // self loop
}
__global__ void k_count_edges(const int* __restrict__ ei, int* __restrict__ counts){
  int e = blockIdx.x*256 + threadIdx.x;
  if(e < NE) atomicAdd(&counts[ei[NE + e]], 1);
}
__global__ void k_scan1(const int* __restrict__ counts, int* __restrict__ bsum){
  __shared__ int sh[256];
  int i = blockIdx.x*256 + threadIdx.x;
  sh[threadIdx.x] = (i < NN) ? counts[i] : 0;
  __syncthreads();
  for(int off = 128; off; off >>= 1){
    if(threadIdx.x < off) sh[threadIdx.x] += sh[threadIdx.x + off];
    __syncthreads();
  }
  if(threadIdx.x == 0) bsum[blockIdx.x] = sh[0];
}
__global__ void k_scan2(int* __restrict__ bsum){
  __shared__ int sh[2][256];
  int t = threadIdx.x;
  sh[0][t] = (t < NSCB) ? bsum[t] : 0;
  __syncthreads();
  int cur = 0;
  for(int off = 1; off < 256; off <<= 1){
    int nxt = cur^1;
    int v = sh[cur][t];
    if(t >= off) v += sh[cur][t-off];
    sh[nxt][t] = v;
    __syncthreads();
    cur = nxt;
  }
  if(t < NSCB) bsum[t] = (t == 0) ? 0 : sh[cur][t-1];
}
__global__ void k_scan3(const int* __restrict__ counts, const int* __restrict__ bsum,
                        int* __restrict__ rowptr, int* __restrict__ cursor,
                        float* __restrict__ dinv, int* __restrict__ srcidx){
  __shared__ int sh[2][256];
  int t = threadIdx.x;
  int i = blockIdx.x*256 + t;
  int c = (i < NN) ? counts[i] : 0;
  sh[0][t] = c;
  __syncthreads();
  int cur = 0;
  for(int off = 1; off < 256; off <<= 1){
    int nxt = cur^1;
    int v = sh[cur][t];
    if(t >= off) v += sh[cur][t-off];
    sh[nxt][t] = v;
    __syncthreads();
    cur = nxt;
  }
  if(i < NN){
    int excl = bsum[blockIdx.x] + sh[cur][t] - c;
    rowptr[i] = excl;
    srcidx[excl] = i;        // self-loop at row start, no atomic needed
    cursor[i] = excl + 1;    // edges fill after it
    dinv[i] = rsqrtf((float)c);
  }
}
__global__ void k_fill(const int* __restrict__ ei, int* __restrict__ cursor,
                       int* __restrict__ srcidx){
  int e = blockIdx.x*256 + threadIdx.x;
  if(e < NE){
    int dst = ei[NE + e];
    int pos = atomicAdd(&cursor[dst], 1);
    srcidx[pos] = ei[e];
  }
}
// after k_fill, cursor[n] == row end for node n.

// ---------------- dense layers ----------------
// 256 threads; 4 output cols/thread (named scalars only — R6 spill lesson);
// per k: one LDS broadcast of X + one ds_read_b128 of W + 4 fmacs.
// Output: bf16 (ushort), optionally prescaled by dinv[row].
template<int KIN, int KOUT, bool SCALE>
__global__ void k_gemm_f(const float* __restrict__ X, const float* __restrict__ W,
                         const float* __restrict__ dinv, unsigned short* __restrict__ Au){
  constexpr int TPR = KOUT/4;          // threads per row
  constexpr int R = 256/TPR;           // rows per block
  __shared__ float Wl[KIN*KOUT];
  __shared__ float Xl[R][KIN+4];       // +4: break stride banking, keep 16B align
  int tid = threadIdx.x;
  for(int i = tid; i < KIN*KOUT/4; i += 256)
    ((float4*)Wl)[i] = ((const float4*)W)[i];
  int row0 = blockIdx.x*R;
  for(int i = tid; i < R*KIN/4; i += 256){
    int r = i/(KIN/4), k4 = i - r*(KIN/4);
    int rr = row0 + r;
    float4 v = (rr < NN) ? ((const float4*)(X + (size_t)rr*KIN))[k4]
                         : make_float4(0.f,0.f,0.f,0.f);
    *(float4*)&Xl[r][k4*4] = v;
  }
  __syncthreads();
  int ty = tid/TPR, tx = tid - ty*TPR;
  int row = row0 + ty;
  if(row >= NN) return;
  float a0=0.f, a1=0.f, a2=0.f, a3=0.f;
#pragma unroll
  for(int k = 0; k < KIN; k++){
    float xv = Xl[ty][k];
    float4 w = *(const float4*)&Wl[k*KOUT + tx*4];
    a0 += xv*w.x; a1 += xv*w.y; a2 += xv*w.z; a3 += xv*w.w;
  }
  float s = SCALE ? dinv[row] : 1.0f;
  ushort4 o;
  o.x = f2bf(a0*s); o.y = f2bf(a1*s); o.z = f2bf(a2*s); o.w = f2bf(a3*s);
  *(ushort4*)(Au + (size_t)row*KOUT + tx*4) = o;
}

// layer-1 variant: X via dtype flag (scalar staging)
template<int KIN, int KOUT, bool SCALE>
__global__ void k_gemm_in(const void* __restrict__ X, const float* __restrict__ W,
                          const float* __restrict__ dinv, unsigned short* __restrict__ Au,
                          const int* __restrict__ flag){
  constexpr int TPR = KOUT/4;
  constexpr int R = 256/TPR;
  __shared__ float Wl[KIN*KOUT];
  __shared__ float Xl[R][KIN+4];
  int tid = threadIdx.x;
  int f = *flag;
  for(int i = tid; i < KIN*KOUT/4; i += 256)
    ((float4*)Wl)[i] = ((const float4*)W)[i];
  int row0 = blockIdx.x*R;
  for(int i = tid; i < R*KIN; i += 256){
    int r = i/KIN, k = i - r*KIN;
    int rr = row0 + r;
    Xl[r][k] = (rr < NN) ? cvt(X, (long long)rr*KIN + k, f) : 0.0f;
  }
  __syncthreads();
  int ty = tid/TPR, tx = tid - ty*TPR;
  int row = row0 + ty;
  if(row >= NN) return;
  float a0=0.f, a1=0.f, a2=0.f, a3=0.f;
#pragma unroll
  for(int k = 0; k < KIN; k++){
    float xv = Xl[ty][k];
    float4 w = *(const float4*)&Wl[k*KOUT + tx*4];
    a0 += xv*w.x; a1 += xv*w.y; a2 += xv*w.z; a3 += xv*w.w;
  }
  float s = SCALE ? dinv[row] : 1.0f;
  ushort4 o;
  o.x = f2bf(a0*s); o.y = f2bf(a1*s); o.z = f2bf(a2*s); o.w = f2bf(a3*s);
  *(ushort4*)(Au + (size_t)row*KOUT + tx*4) = o;
}

// per (node, head) attention scores from bf16 features
template<int C>
__global__ void k_gat_scores(const unsigned short* __restrict__ Au, const float* __restrict__ asrc,
                             const float* __restrict__ adst, float* __restrict__ sS, float* __restrict__ sD){
  int i = blockIdx.x*256 + threadIdx.x;
  if(i >= NN*2) return;
  int node = i >> 1, h = i & 1;
  const unsigned short* hp = Au + (size_t)node*2*C + h*C;
  float s = 0.0f, d = 0.0f;
#pragma unroll
  for(int c = 0; c < C; c++){
    float v = bf2f(hp[c]);
    s += v * asrc[h*C + c];
    d += v * adst[h*C + c];
  }
  sS[i] = s; sD[i] = d;
}

// head-interleave pack: Ab[n*64+c] = (bf16 h0[c]) | (bf16 h1[c] << 16)
__global__ void k_pack1(const unsigned short* __restrict__ Au, unsigned* __restrict__ Ab){
  int i = blockIdx.x*256 + threadIdx.x;
  if(i >= NN*64) return;
  int node = i >> 6, c = i & 63;
  unsigned lo = Au[(size_t)node*128 + c];
  unsigned hi = Au[(size_t)node*128 + 64 + c];
  Ab[i] = lo | (hi << 16);
}
__global__ void k_pack2(const unsigned short* __restrict__ Au, unsigned* __restrict__ Ab){
  int i = blockIdx.x*256 + threadIdx.x;
  if(i >= NN*32) return;
  int node = i >> 5, c = i & 31;
  unsigned lo = Au[(size_t)node*64 + c];
  unsigned hi = Au[(size_t)node*64 + 32 + c];
  Ab[i] = lo | (hi << 16);
}

// ---------------- gather aggregations (one wave per dst node) ----------------
// GCN: Au is bf16, prescaled by dinv[src] in GEMM epilogue.
__global__ void k_gcn_gather(const int* __restrict__ rowptr, const int* __restrict__ rowend,
                             const int* __restrict__ srcidx, const float* __restrict__ dinv,
                             const unsigned short* __restrict__ Au, const float* __restrict__ bias,
                             float* __restrict__ B){
  int wid = threadIdx.x >> 6, lane = threadIdx.x & 63;
  int n = blockIdx.x*4 + wid;
  if(n >= NN) return;
  int s0 = rowptr[n], ne = rowend[n] - s0;
  float acc = 0.0f;
  for(int base = 0; base < ne; base += 64){
    int my = base + lane;
    int src = (my < ne) ? srcidx[s0 + my] : 0;
    int cnt = min(64, ne - base);
#pragma unroll 4
    for(int j = 0; j < cnt; j++){
      int sb = __shfl(src, j);
      acc += bf2f(Au[(size_t)sb*64 + lane]);
    }
  }
  float v = acc*dinv[n] + bias[lane];
  B[(size_t)n*64 + lane] = fmaxf(v, 0.0f);
}

// GAT1 (heads=2, C=64, concat): segment-softmax + aggregate + bias + relu.
// Gather reads head-interleaved bf16 pairs: one dword per lane per edge.
__global__ void k_gat1_gather(const int* __restrict__ rowptr, const int* __restrict__ rowend,
                              const int* __restrict__ srcidx, const float* __restrict__ sS,
                              const float* __restrict__ sD, const unsigned* __restrict__ Ab,
                              const float* __restrict__ bias, float* __restrict__ B){
  int wid = threadIdx.x >> 6, lane = threadIdx.x & 63;
  int n = blockIdx.x*4 + wid;
  if(n >= NN) return;
  int s0 = rowptr[n], ne = rowend[n] - s0;
  float d0 = sD[n*2], d1 = sD[n*2+1];
  float m0 = -1e30f, z0 = 0.0f, m1 = -1e30f, z1 = 0.0f;
  for(int i = lane; i < ne; i += 64){
    int src = srcidx[s0 + i];
    float2 sv = *(const float2*)(sS + src*2);
    float e0 = sv.x + d0; e0 = e0 > 0.0f ? e0 : 0.2f*e0;
    float e1 = sv.y + d1; e1 = e1 > 0.0f ? e1 : 0.2f*e1;
    if(e0 > m0){ z0 *= __expf(m0 - e0); m0 = e0; }
    z0 += __expf(e0 - m0);
    if(e1 > m1){ z1 *= __expf(m1 - e1); m1 = e1; }
    z1 += __expf(e1 - m1);
  }
  for(int off = 32; off; off >>= 1){
    float mo = __shfl_xor(m0, off), zo = __shfl_xor(z0, off);
    float mn = fmaxf(m0, mo);
    z0 = z0*__expf(m0 - mn) + zo*__expf(mo - mn); m0 = mn;
    mo = __shfl_xor(m1, off); zo = __shfl_xor(z1, off);
    mn = fmaxf(m1, mo);
    z1 = z1*__expf(m1 - mn) + zo*__expf(mo - mn); m1 = mn;
  }
  float acc0 = 0.0f, acc1 = 0.0f;
  for(int base = 0; base < ne; base += 64){
    int my = base + lane;
    int src = 0; float w0 = 0.0f, w1 = 0.0f;
    if(my < ne){
      src = srcidx[s0 + my];
      float2 sv = *(const float2*)(sS + src*2);
      float e0 = sv.x + d0; e0 = e0 > 0.0f ? e0 : 0.2f*e0;
      float e1 = sv.y + d1; e1 = e1 > 0.0f ? e1 : 0.2f*e1;
      w0 = __expf(e0 - m0); w1 = __expf(e1 - m1);
    }
    int cnt = min(64, ne - base);
#pragma unroll 4
    for(int j = 0; j < cnt; j++){
      int sb = __shfl(src, j);
      float a0 = __shfl(w0, j), a1 = __shfl(w1, j);
      unsigned p = Ab[(size_t)sb*64 + lane];
      acc0 += __uint_as_float(p << 16)         * a0;
      acc1 += __uint_as_float(p & 0xffff0000u) * a1;
    }
  }
  float o0 = acc0/(z0 + 1e-16f) + bias[lane];
  float o1 = acc1/(z1 + 1e-16f) + bias[64 + lane];
  B[(size_t)n*128 + lane]      = fmaxf(o0, 0.0f);
  B[(size_t)n*128 + 64 + lane] = fmaxf(o1, 0.0f);
}

// GAT2 (heads=2, C=32, mean) + bias + log_softmax + dtype-flagged output
__global__ void k_gat2_final(const int* __restrict__ rowptr, const int* __restrict__ rowend,
                             const int* __restrict__ srcidx, const float* __restrict__ sS,
                             const float* __restrict__ sD, const unsigned* __restrict__ Ab,
                             const float* __restrict__ bias, void* __restrict__ out,
                             const int* __restrict__ flag){
  int wid = threadIdx.x >> 6, lane = threadIdx.x & 63;
  int n = blockIdx.x*4 + wid;
  if(n >= NN) return;
  int s0 = rowptr[n], ne = rowend[n] - s0;
  float d0 = sD[n*2], d1 = sD[n*2+1];
  float m0 = -1e30f, z0 = 0.0f, m1 = -1e30f, z1 = 0.0f;
  for(int i = lane; i < ne; i += 64){
    int src = srcidx[s0 + i];
    float2 sv = *(const float2*)(sS + src*2);
    float e0 = sv.x + d0; e0 = e0 > 0.0f ? e0 : 0.2f*e0;
    float e1 = sv.y + d1; e1 = e1 > 0.0f ? e1 : 0.2f*e1;
    if(e0 > m0){ z0 *= __expf(m0 - e0); m0 = e0; }
    z0 += __expf(e0 - m0);
    if(e1 > m1){ z1 *= __expf(m1 - e1); m1 = e1; }
    z1 += __expf(e1 - m1);
  }
  for(int off = 32; off; off >>= 1){
    float mo = __shfl_xor(m0, off), zo = __shfl_xor(z0, off);
    float mn = fmaxf(m0, mo);
    z0 = z0*__expf(m0 - mn) + zo*__expf(mo - mn); m0 = mn;
    mo = __shfl_xor(m1, off); zo = __shfl_xor(z1, off);
    mn = fmaxf(m1, mo);
    z1 = z1*__expf(m1 - mn) + zo*__expf(mo - mn); m1 = mn;
  }
  float acc = 0.0f;
  for(int base = 0; base < ne; base += 64){
    int my = base + lane;
    int src = 0; float w0 = 0.0f, w1 = 0.0f;
    if(my < ne){
      src = srcidx[s0 + my];
      float2 sv = *(const float2*)(sS + src*2);
      float e0 = sv.x + d0; e0 = e0 > 0.0f ? e0 : 0.2f*e0;
      float e1 = sv.y + d1; e1 = e1 > 0.0f ? e1 : 0.2f*e1;
      w0 = __expf(e0 - m0); w1 = __expf(e1 - m1);
    }
    int cnt = min(64, ne - base);
#pragma unroll 4
    for(int j = 0; j < cnt; j++){
      int sb = __shfl(src, j);
      float a0 = __shfl(w0, j), a1 = __shfl(w1, j);
      unsigned p = Ab[(size_t)sb*32 + (lane & 31)];
      float v = (lane < 32) ? __uint_as_float(p << 16) : __uint_as_float(p & 0xffff0000u);
      acc += v * ((lane < 32) ? a0 : a1);
    }
  }
  float zh = (lane < 32) ? z0 : z1;
  float o = acc/(zh + 1e-16f);
  float o2 = __shfl_down(o, 32);               // lane<32 gets head-1 partner
  o = 0.5f*(o + o2) + ((lane < 32) ? bias[lane] : 0.0f);
  float mx = o;
  for(int off = 16; off; off >>= 1) mx = fmaxf(mx, __shfl_xor(mx, off, 32));
  float s = __expf(o - mx);
  for(int off = 16; off; off >>= 1) s += __shfl_xor(s, off, 32);
  float r = o - (mx + __logf(s));
  if(lane < 32){
    if(*flag) ((float*)out)[(size_t)n*32 + lane] = r;
    else      ((bf16*)out)[(size_t)n*32 + lane] = __float2bfloat16(r);
  }
}

extern "C" void kernel_launch(void* const* d_in, const int* in_sizes, int n_in,
                              void* d_out, int out_size, void* d_ws, size_t ws_size,
                              hipStream_t stream) {
  const void* x   = d_in[0];
  const int*  ei  = (const int*)d_in[1];

  // workspace layout (same total footprint as R7):
  // A-region 25.6MB: Au bf16 [<=NN*128] | Ab u32 [<=NN*64] (at +12.8MB)
  // then B[NN*128] f32 | dinv | sS | sD | rowptr | cursor | counts | bsum | srcidx | Wc | flag
  float* A    = (float*)d_ws;
  unsigned short* Au = (unsigned short*)A;
  unsigned* Ab = (unsigned*)(A + (size_t)NN*64);   // +12.8MB
  float* B    = A + (size_t)NN*128;
  float* dinv = B + (size_t)NN*128;
  float* sS   = dinv + NN;
  float* sD   = sS + 2*NN;
  int* rowptr = (int*)(sD + 2*NN);
  int* cursor = rowptr + NN;
  int* counts = cursor + NN;
  int* bsum   = counts + NN;
  int* srcidx = bsum + 256;
  float* Wc   = (float*)(srcidx + NT);
  int*  flag  = (int*)(Wc + 29344);

  const float* W1c  = Wc;
  const float* b1c  = Wc + 8192;
  const float* W2c  = Wc + 8256;
  const float* b2c  = Wc + 12352;
  const float* Wg1c = Wc + 12416;
  const float* as1c = Wc + 20608;
  const float* ad1c = Wc + 20736;
  const float* bg1c = Wc + 20864;
  const float* Wg2c = Wc + 20992;
  const float* as2c = Wc + 29184;
  const float* ad2c = Wc + 29248;
  const float* bg2c = Wc + 29312;

  auto nb = [](long long t){ return dim3((unsigned)((t + 255)/256)); };
  dim3 gnodes((NN + 3)/4);      // 4 waves/block, 1 wave per node

  // dtype detect + weight conversion
  k_detect<<<1, 256, 0, stream>>>(d_in[2], 8192, flag);
  SrcPtrs sp;
  for(int i = 0; i < 12; i++) sp.p[i] = d_in[2 + i];
  k_cvtall<<<12, 256, 0, stream>>>(sp, Wc, flag);

  // CSR build (shared by all 4 aggregations) — 3-phase parallel scan
  k_init_counts<<<nb(NN), 256, 0, stream>>>(counts);
  k_count_edges<<<nb(NE), 256, 0, stream>>>(ei, counts);
  k_scan1<<<NSCB, 256, 0, stream>>>(counts, bsum);
  k_scan2<<<1, 256, 0, stream>>>(bsum);
  k_scan3<<<NSCB, 256, 0, stream>>>(counts, bsum, rowptr, cursor, dinv, srcidx);
  k_fill<<<nb(NE), 256, 0, stream>>>(ei, cursor, srcidx);
  // after k_fill: cursor[n] == row end

  // ---- GCN1 ----  (GEMM prescales rows by dinv, writes bf16)
  k_gemm_in<128,64,true><<<dim3((NN+15)/16), 256, 0, stream>>>(x, W1c, dinv, Au, flag);
  k_gcn_gather<<<gnodes, 256, 0, stream>>>(rowptr, cursor, srcidx, dinv, Au, b1c, B);

  // ---- GCN2 ----
  k_gemm_f<64,64,true><<<dim3((NN+15)/16), 256, 0, stream>>>(B, W2c, dinv, Au);
  k_gcn_gather<<<gnodes, 256, 0, stream>>>(rowptr, cursor, srcidx, dinv, Au, b2c, B);

  // ---- GAT1: heads=2, C=64, concat ----
  k_gemm_f<64,128,false><<<dim3((NN+7)/8), 256, 0, stream>>>(B, Wg1c, dinv, Au);
  k_gat_scores<64><<<nb((long long)NN*2), 256, 0, stream>>>(Au, as1c, ad1c, sS, sD);
  k_pack1<<<nb((long long)NN*64), 256, 0, stream>>>(Au, Ab);
  k_gat1_gather<<<gnodes, 256, 0, stream>>>(rowptr, cursor, srcidx, sS, sD, Ab, bg1c, B);

  // ---- GAT2: heads=2, C=32, mean + log_softmax ----
  k_gemm_f<128,64,false><<<dim3((NN+15)/16), 256, 0, stream>>>(B, Wg2c, dinv, Au);
  k_gat_scores<32><<<nb((long long)NN*2), 256, 0, stream>>>(Au, as2c, ad2c, sS, sD);
  k_pack2<<<nb((long long)NN*32), 256, 0, stream>>>(Au, Ab);
  k_gat2_final<<<gnodes, 256, 0, stream>>>(rowptr, cursor, srcidx, sS, sD, Ab, bg2c, d_out, flag);
}

// Round 9
// 460.985 us; speedup vs baseline: 8.2573x; 1.2060x over previous
//
#include <hip/hip_runtime.h>
#include <hip/hip_bf16.h>

typedef __hip_bfloat16 bf16;

constexpr int NN = 50000;           // nodes
constexpr int NE = 800000;          // edges (without self loops)
constexpr int NT = NE + NN;         // edges incl self loops
constexpr int NSCB = (NN + 255)/256; // 196 scan blocks

// flag-selected load: f32 storage vs bf16 storage
__device__ __forceinline__ float cvt(const void* p, long long i, int f32){
  return f32 ? ((const float*)p)[i] : __bfloat162float(((const bf16*)p)[i]);
}
// bf16 <-> f32 (RNE pack)
__device__ __forceinline__ unsigned short f2bf(float f){
  unsigned u = __float_as_uint(f);
  u += 0x7fffu + ((u >> 16) & 1);
  return (unsigned short)(u >> 16);
}
__device__ __forceinline__ float bflo(unsigned p){ return __uint_as_float(p << 16); }
__device__ __forceinline__ float bfhi(unsigned p){ return __uint_as_float(p & 0xffff0000u); }

// Storage-dtype detector (see R2 notes): flag=1 => f32 storage, 0 => bf16.
__global__ void k_detect(const void* w, int n, int* flag){
  __shared__ int bad;
  if(threadIdx.x == 0) bad = 0;
  __syncthreads();
  const unsigned short* p = (const unsigned short*)w;
  int local = 0;
  for(int i = threadIdx.x; i < n; i += 256){
    int e = (p[i] >> 7) & 0xFF;
    if(e >= 0xC0) local = 1;
  }
  if(local) atomicOr(&bad, 1);
  __syncthreads();
  if(threadIdx.x == 0) *flag = bad;
}

struct SrcPtrs { const void* p[12]; };
__global__ void k_cvtall(SrcPtrs sp, float* Wc, const int* flag){
  const int sz[12]  = {8192,64,4096,64,8192,128,128,128,8192,64,64,32};
  const int off[12] = {0,8192,8256,12352,12416,20608,20736,20864,20992,29184,29248,29312};
  int b = blockIdx.x;
  int f = *flag;
  const void* src = sp.p[b];
  float* dst = Wc + off[b];
  int n = sz[b];
  for(int i = threadIdx.x; i < n; i += 256) dst[i] = cvt(src, i, f);
}

// ---------------- CSR build (dst-bucketed, self-loops included) ----------------
__global__ void k_init_counts(int* __restrict__ counts){
  int i = blockIdx.x*256 + threadIdx.x;
  if(i < NN) counts[i] = 1;          // self loop
}
__global__ void k_count_edges(const int* __restrict__ ei, int* __restrict__ counts){
  int e = blockIdx.x*256 + threadIdx.x;
  if(e < NE) atomicAdd(&counts[ei[NE + e]], 1);
}
__global__ void k_scan1(const int* __restrict__ counts, int* __restrict__ bsum){
  __shared__ int sh[256];
  int i = blockIdx.x*256 + threadIdx.x;
  sh[threadIdx.x] = (i < NN) ? counts[i] : 0;
  __syncthreads();
  for(int off = 128; off; off >>= 1){
    if(threadIdx.x < off) sh[threadIdx.x] += sh[threadIdx.x + off];
    __syncthreads();
  }
  if(threadIdx.x == 0) bsum[blockIdx.x] = sh[0];
}
__global__ void k_scan2(int* __restrict__ bsum){
  __shared__ int sh[2][256];
  int t = threadIdx.x;
  sh[0][t] = (t < NSCB) ? bsum[t] : 0;
  __syncthreads();
  int cur = 0;
  for(int off = 1; off < 256; off <<= 1){
    int nxt = cur^1;
    int v = sh[cur][t];
    if(t >= off) v += sh[cur][t-off];
    sh[nxt][t] = v;
    __syncthreads();
    cur = nxt;
  }
  if(t < NSCB) bsum[t] = (t == 0) ? 0 : sh[cur][t-1];
}
__global__ void k_scan3(const int* __restrict__ counts, const int* __restrict__ bsum,
                        int* __restrict__ rowptr, int* __restrict__ cursor,
                        float* __restrict__ dinv, int* __restrict__ srcidx){
  __shared__ int sh[2][256];
  int t = threadIdx.x;
  int i = blockIdx.x*256 + t;
  int c = (i < NN) ? counts[i] : 0;
  sh[0][t] = c;
  __syncthreads();
  int cur = 0;
  for(int off = 1; off < 256; off <<= 1){
    int nxt = cur^1;
    int v = sh[cur][t];
    if(t >= off) v += sh[cur][t-off];
    sh[nxt][t] = v;
    __syncthreads();
    cur = nxt;
  }
  if(i < NN){
    int excl = bsum[blockIdx.x] + sh[cur][t] - c;
    rowptr[i] = excl;
    srcidx[excl] = i;        // self-loop at row start, no atomic needed
    cursor[i] = excl + 1;    // edges fill after it
    dinv[i] = rsqrtf((float)c);
  }
}
__global__ void k_fill(const int* __restrict__ ei, int* __restrict__ cursor,
                       int* __restrict__ srcidx){
  int e = blockIdx.x*256 + threadIdx.x;
  if(e < NE){
    int dst = ei[NE + e];
    int pos = atomicAdd(&cursor[dst], 1);
    srcidx[pos] = ei[e];
  }
}
// after k_fill, cursor[n] == row end for node n.

// ---------------- dense layers (R8 structure, bf16 output) ----------------
template<int KIN, int KOUT, bool SCALE>
__global__ void k_gemm_f(const float* __restrict__ X, const float* __restrict__ W,
                         const float* __restrict__ dinv, unsigned short* __restrict__ Au){
  constexpr int TPR = KOUT/4;          // threads per row
  constexpr int R = 256/TPR;           // rows per block
  __shared__ float Wl[KIN*KOUT];
  __shared__ float Xl[R][KIN+4];
  int tid = threadIdx.x;
  for(int i = tid; i < KIN*KOUT/4; i += 256)
    ((float4*)Wl)[i] = ((const float4*)W)[i];
  int row0 = blockIdx.x*R;
  for(int i = tid; i < R*KIN/4; i += 256){
    int r = i/(KIN/4), k4 = i - r*(KIN/4);
    int rr = row0 + r;
    float4 v = (rr < NN) ? ((const float4*)(X + (size_t)rr*KIN))[k4]
                         : make_float4(0.f,0.f,0.f,0.f);
    *(float4*)&Xl[r][k4*4] = v;
  }
  __syncthreads();
  int ty = tid/TPR, tx = tid - ty*TPR;
  int row = row0 + ty;
  if(row >= NN) return;
  float a0=0.f, a1=0.f, a2=0.f, a3=0.f;
#pragma unroll
  for(int k = 0; k < KIN; k++){
    float xv = Xl[ty][k];
    float4 w = *(const float4*)&Wl[k*KOUT + tx*4];
    a0 += xv*w.x; a1 += xv*w.y; a2 += xv*w.z; a3 += xv*w.w;
  }
  float s = SCALE ? dinv[row] : 1.0f;
  ushort4 o;
  o.x = f2bf(a0*s); o.y = f2bf(a1*s); o.z = f2bf(a2*s); o.w = f2bf(a3*s);
  *(ushort4*)(Au + (size_t)row*KOUT + tx*4) = o;
}

template<int KIN, int KOUT, bool SCALE>
__global__ void k_gemm_in(const void* __restrict__ X, const float* __restrict__ W,
                          const float* __restrict__ dinv, unsigned short* __restrict__ Au,
                          const int* __restrict__ flag){
  constexpr int TPR = KOUT/4;
  constexpr int R = 256/TPR;
  __shared__ float Wl[KIN*KOUT];
  __shared__ float Xl[R][KIN+4];
  int tid = threadIdx.x;
  int f = *flag;
  for(int i = tid; i < KIN*KOUT/4; i += 256)
    ((float4*)Wl)[i] = ((const float4*)W)[i];
  int row0 = blockIdx.x*R;
  for(int i = tid; i < R*KIN; i += 256){
    int r = i/KIN, k = i - r*KIN;
    int rr = row0 + r;
    Xl[r][k] = (rr < NN) ? cvt(X, (long long)rr*KIN + k, f) : 0.0f;
  }
  __syncthreads();
  int ty = tid/TPR, tx = tid - ty*TPR;
  int row = row0 + ty;
  if(row >= NN) return;
  float a0=0.f, a1=0.f, a2=0.f, a3=0.f;
#pragma unroll
  for(int k = 0; k < KIN; k++){
    float xv = Xl[ty][k];
    float4 w = *(const float4*)&Wl[k*KOUT + tx*4];
    a0 += xv*w.x; a1 += xv*w.y; a2 += xv*w.z; a3 += xv*w.w;
  }
  float s = SCALE ? dinv[row] : 1.0f;
  ushort4 o;
  o.x = f2bf(a0*s); o.y = f2bf(a1*s); o.z = f2bf(a2*s); o.w = f2bf(a3*s);
  *(ushort4*)(Au + (size_t)row*KOUT + tx*4) = o;
}

// per (node, head) attention scores from bf16 features (dword-paired loads)
template<int C>
__global__ void k_gat_scores(const unsigned* __restrict__ Au32, const float* __restrict__ asrc,
                             const float* __restrict__ adst, float* __restrict__ sS, float* __restrict__ sD){
  int i = blockIdx.x*256 + threadIdx.x;
  if(i >= NN*2) return;
  int node = i >> 1, h = i & 1;
  const unsigned* hp = Au32 + ((size_t)node*2*C + h*C)/2;
  float s = 0.0f, d = 0.0f;
#pragma unroll
  for(int c = 0; c < C/2; c++){
    unsigned p = hp[c];
    float v0 = bflo(p), v1 = bfhi(p);
    s += v0*asrc[h*C + 2*c] + v1*asrc[h*C + 2*c + 1];
    d += v0*adst[h*C + 2*c] + v1*adst[h*C + 2*c + 1];
  }
  sS[i] = s; sD[i] = d;
}

// head-interleave pack: Ab[n*64+c] = (bf16 h0[c]) | (bf16 h1[c] << 16)
__global__ void k_pack1(const unsigned short* __restrict__ Au, unsigned* __restrict__ Ab){
  int i = blockIdx.x*256 + threadIdx.x;
  if(i >= NN*64) return;
  int node = i >> 6, c = i & 63;
  unsigned lo = Au[(size_t)node*128 + c];
  unsigned hi = Au[(size_t)node*128 + 64 + c];
  Ab[i] = lo | (hi << 16);
}
__global__ void k_pack2(const unsigned short* __restrict__ Au, unsigned* __restrict__ Ab){
  int i = blockIdx.x*256 + threadIdx.x;
  if(i >= NN*32) return;
  int node = i >> 5, c = i & 31;
  unsigned lo = Au[(size_t)node*64 + c];
  unsigned hi = Au[(size_t)node*64 + 32 + c];
  Ab[i] = lo | (hi << 16);
}

// ---------------- gather aggregations ----------------
// GCN: quarter-wave per edge (4 edges/iter); Au row = 64 bf16 = 16 uint2.
// q = lane>>4 edge parity, c2 = lane&15 -> channels 4c2..4c2+3 via one uint2.
__global__ void k_gcn_gather(const int* __restrict__ rowptr, const int* __restrict__ rowend,
                             const int* __restrict__ srcidx, const float* __restrict__ dinv,
                             const unsigned* __restrict__ Au32, const float* __restrict__ bias,
                             float* __restrict__ B){
  int wid = threadIdx.x >> 6, lane = threadIdx.x & 63;
  int n = blockIdx.x*4 + wid;
  if(n >= NN) return;
  int s0 = rowptr[n], ne = rowend[n] - s0;
  int q = lane >> 4, c2 = lane & 15;
  float a0=0.f, a1=0.f, a2=0.f, a3=0.f;
  for(int base = 0; base < ne; base += 64){
    int my = base + lane;
    int src = (my < ne) ? srcidx[s0 + my] : -1;
    int cnt = min(64, ne - base);
    int iters = (cnt + 3) >> 2;
#pragma unroll 4
    for(int j = 0; j < iters; j++){
      int sb = __shfl(src, 4*j + q);
      if(sb >= 0){
        uint2 p = *(const uint2*)(Au32 + (size_t)sb*32 + c2*2);
        a0 += bflo(p.x); a1 += bfhi(p.x);
        a2 += bflo(p.y); a3 += bfhi(p.y);
      }
    }
  }
  a0 += __shfl_xor(a0, 16); a0 += __shfl_xor(a0, 32);
  a1 += __shfl_xor(a1, 16); a1 += __shfl_xor(a1, 32);
  a2 += __shfl_xor(a2, 16); a2 += __shfl_xor(a2, 32);
  a3 += __shfl_xor(a3, 16); a3 += __shfl_xor(a3, 32);
  if(q == 0){
    float dn = dinv[n];
    float4 o;
    o.x = fmaxf(a0*dn + bias[4*c2+0], 0.0f);
    o.y = fmaxf(a1*dn + bias[4*c2+1], 0.0f);
    o.z = fmaxf(a2*dn + bias[4*c2+2], 0.0f);
    o.w = fmaxf(a3*dn + bias[4*c2+3], 0.0f);
    *(float4*)(B + (size_t)n*64 + 4*c2) = o;
  }
}

// GAT1 (heads=2, C=64, concat): half-wave per edge (2 edges/iter).
// Ab row = 64 dwords = 32 uint2; half = lane>>5, c2 = lane&31 -> channels 2c2,2c2+1 x both heads.
__global__ void k_gat1_gather(const int* __restrict__ rowptr, const int* __restrict__ rowend,
                              const int* __restrict__ srcidx, const float* __restrict__ sS,
                              const float* __restrict__ sD, const unsigned* __restrict__ Ab,
                              const float* __restrict__ bias, float* __restrict__ B){
  int wid = threadIdx.x >> 6, lane = threadIdx.x & 63;
  int n = blockIdx.x*4 + wid;
  if(n >= NN) return;
  int s0 = rowptr[n], ne = rowend[n] - s0;
  float d0 = sD[n*2], d1 = sD[n*2+1];
  // phase A: per-lane online (m,z) per head over strided edges
  float m0 = -1e30f, z0 = 0.0f, m1 = -1e30f, z1 = 0.0f;
  for(int i = lane; i < ne; i += 64){
    int src = srcidx[s0 + i];
    float2 sv = *(const float2*)(sS + src*2);
    float e0 = sv.x + d0; e0 = e0 > 0.0f ? e0 : 0.2f*e0;
    float e1 = sv.y + d1; e1 = e1 > 0.0f ? e1 : 0.2f*e1;
    if(e0 > m0){ z0 *= __expf(m0 - e0); m0 = e0; }
    z0 += __expf(e0 - m0);
    if(e1 > m1){ z1 *= __expf(m1 - e1); m1 = e1; }
    z1 += __expf(e1 - m1);
  }
  for(int off = 32; off; off >>= 1){
    float mo = __shfl_xor(m0, off), zo = __shfl_xor(z0, off);
    float mn = fmaxf(m0, mo);
    z0 = z0*__expf(m0 - mn) + zo*__expf(mo - mn); m0 = mn;
    mo = __shfl_xor(m1, off); zo = __shfl_xor(z1, off);
    mn = fmaxf(m1, mo);
    z1 = z1*__expf(m1 - mn) + zo*__expf(mo - mn); m1 = mn;
  }
  int half = lane >> 5, c2 = lane & 31;
  float ah0c0=0.f, ah0c1=0.f, ah1c0=0.f, ah1c1=0.f;
  for(int base = 0; base < ne; base += 64){
    int my = base + lane;
    int src = 0; float w0 = 0.0f, w1 = 0.0f;
    if(my < ne){
      src = srcidx[s0 + my];
      float2 sv = *(const float2*)(sS + src*2);
      float e0 = sv.x + d0; e0 = e0 > 0.0f ? e0 : 0.2f*e0;
      float e1 = sv.y + d1; e1 = e1 > 0.0f ? e1 : 0.2f*e1;
      w0 = __expf(e0 - m0); w1 = __expf(e1 - m1);
    }
    int cnt = min(64, ne - base);
    int iters = (cnt + 1) >> 1;
#pragma unroll 4
    for(int j = 0; j < iters; j++){
      int idx = 2*j + half;
      int sb = __shfl(src, idx);
      float a0 = __shfl(w0, idx), a1 = __shfl(w1, idx);
      uint2 p = *(const uint2*)(Ab + (size_t)sb*64 + c2*2);
      ah0c0 += bflo(p.x)*a0; ah1c0 += bfhi(p.x)*a1;
      ah0c1 += bflo(p.y)*a0; ah1c1 += bfhi(p.y)*a1;
    }
  }
  ah0c0 += __shfl_xor(ah0c0, 32);
  ah0c1 += __shfl_xor(ah0c1, 32);
  ah1c0 += __shfl_xor(ah1c0, 32);
  ah1c1 += __shfl_xor(ah1c1, 32);
  if(half == 0){
    float iz0 = 1.0f/(z0 + 1e-16f), iz1 = 1.0f/(z1 + 1e-16f);
    float2 o0, o1;
    o0.x = fmaxf(ah0c0*iz0 + bias[2*c2],        0.0f);
    o0.y = fmaxf(ah0c1*iz0 + bias[2*c2+1],      0.0f);
    o1.x = fmaxf(ah1c0*iz1 + bias[64 + 2*c2],   0.0f);
    o1.y = fmaxf(ah1c1*iz1 + bias[64 + 2*c2+1], 0.0f);
    *(float2*)(B + (size_t)n*128 + 2*c2)      = o0;
    *(float2*)(B + (size_t)n*128 + 64 + 2*c2) = o1;
  }
}

// GAT2 (heads=2, C=32, mean) + bias + log_softmax: quarter-wave per edge (4 edges/iter).
// Ab row = 32 dwords = 16 uint2; q = lane>>4, c2 = lane&15 -> channels 2c2,2c2+1 x both heads.
__global__ void k_gat2_final(const int* __restrict__ rowptr, const int* __restrict__ rowend,
                             const int* __restrict__ srcidx, const float* __restrict__ sS,
                             const float* __restrict__ sD, const unsigned* __restrict__ Ab,
                             const float* __restrict__ bias, void* __restrict__ out,
                             const int* __restrict__ flag){
  int wid = threadIdx.x >> 6, lane = threadIdx.x & 63;
  int n = blockIdx.x*4 + wid;
  if(n >= NN) return;
  int s0 = rowptr[n], ne = rowend[n] - s0;
  float d0 = sD[n*2], d1 = sD[n*2+1];
  float m0 = -1e30f, z0 = 0.0f, m1 = -1e30f, z1 = 0.0f;
  for(int i = lane; i < ne; i += 64){
    int src = srcidx[s0 + i];
    float2 sv = *(const float2*)(sS + src*2);
    float e0 = sv.x + d0; e0 = e0 > 0.0f ? e0 : 0.2f*e0;
    float e1 = sv.y + d1; e1 = e1 > 0.0f ? e1 : 0.2f*e1;
    if(e0 > m0){ z0 *= __expf(m0 - e0); m0 = e0; }
    z0 += __expf(e0 - m0);
    if(e1 > m1){ z1 *= __expf(m1 - e1); m1 = e1; }
    z1 += __expf(e1 - m1);
  }
  for(int off = 32; off; off >>= 1){
    float mo = __shfl_xor(m0, off), zo = __shfl_xor(z0, off);
    float mn = fmaxf(m0, mo);
    z0 = z0*__expf(m0 - mn) + zo*__expf(mo - mn); m0 = mn;
    mo = __shfl_xor(m1, off); zo = __shfl_xor(z1, off);
    mn = fmaxf(m1, mo);
    z1 = z1*__expf(m1 - mn) + zo*__expf(mo - mn); m1 = mn;
  }
  int q = lane >> 4, c2 = lane & 15;
  float ah0c0=0.f, ah0c1=0.f, ah1c0=0.f, ah1c1=0.f;
  for(int base = 0; base < ne; base += 64){
    int my = base + lane;
    int src = 0; float w0 = 0.0f, w1 = 0.0f;
    if(my < ne){
      src = srcidx[s0 + my];
      float2 sv = *(const float2*)(sS + src*2);
      float e0 = sv.x + d0; e0 = e0 > 0.0f ? e0 : 0.2f*e0;
      float e1 = sv.y + d1; e1 = e1 > 0.0f ? e1 : 0.2f*e1;
      w0 = __expf(e0 - m0); w1 = __expf(e1 - m1);
    }
    int cnt = min(64, ne - base);
    int iters = (cnt + 3) >> 2;
#pragma unroll 4
    for(int j = 0; j < iters; j++){
      int idx = 4*j + q;
      int sb = __shfl(src, idx);
      float a0 = __shfl(w0, idx), a1 = __shfl(w1, idx);
      uint2 p = *(const uint2*)(Ab + (size_t)sb*32 + c2*2);
      ah0c0 += bflo(p.x)*a0; ah1c0 += bfhi(p.x)*a1;
      ah0c1 += bflo(p.y)*a0; ah1c1 += bfhi(p.y)*a1;
    }
  }
  ah0c0 += __shfl_xor(ah0c0, 16); ah0c0 += __shfl_xor(ah0c0, 32);
  ah0c1 += __shfl_xor(ah0c1, 16); ah0c1 += __shfl_xor(ah0c1, 32);
  ah1c0 += __shfl_xor(ah1c0, 16); ah1c0 += __shfl_xor(ah1c0, 32);
  ah1c1 += __shfl_xor(ah1c1, 16); ah1c1 += __shfl_xor(ah1c1, 32);
  float iz0 = 1.0f/(z0 + 1e-16f), iz1 = 1.0f/(z1 + 1e-16f);
  float o0 = 0.5f*(ah0c0*iz0 + ah1c0*iz1) + bias[2*c2];
  float o1 = 0.5f*(ah0c1*iz0 + ah1c1*iz1) + bias[2*c2+1];
  // log_softmax over 32 channels: 16 lanes x 2 values (all quarters identical)
  float mx = fmaxf(o0, o1);
  for(int off = 8; off; off >>= 1) mx = fmaxf(mx, __shfl_xor(mx, off, 16));
  float s = __expf(o0 - mx) + __expf(o1 - mx);
  for(int off = 8; off; off >>= 1) s += __shfl_xor(s, off, 16);
  float lse = mx + __logf(s);
  if(q == 0){
    float r0 = o0 - lse, r1 = o1 - lse;
    if(*flag){
      float2 r; r.x = r0; r.y = r1;
      ((float2*)out)[(size_t)n*16 + c2] = r;
    } else {
      ((unsigned*)out)[(size_t)n*16 + c2] = (unsigned)f2bf(r0) | ((unsigned)f2bf(r1) << 16);
    }
  }
}

extern "C" void kernel_launch(void* const* d_in, const int* in_sizes, int n_in,
                              void* d_out, int out_size, void* d_ws, size_t ws_size,
                              hipStream_t stream) {
  const void* x   = d_in[0];
  const int*  ei  = (const int*)d_in[1];

  // workspace layout:
  // A-region 25.6MB: Au bf16 [<=NN*128] | Ab u32 [<=NN*64] (at +12.8MB)
  // then B[NN*128] f32 | dinv | sS | sD | rowptr | cursor | counts | bsum | srcidx | Wc | flag
  float* A    = (float*)d_ws;
  unsigned short* Au = (unsigned short*)A;
  unsigned* Au32 = (unsigned*)A;
  unsigned* Ab = (unsigned*)(A + (size_t)NN*64);   // +12.8MB
  float* B    = A + (size_t)NN*128;
  float* dinv = B + (size_t)NN*128;
  float* sS   = dinv + NN;
  float* sD   = sS + 2*NN;
  int* rowptr = (int*)(sD + 2*NN);
  int* cursor = rowptr + NN;
  int* counts = cursor + NN;
  int* bsum   = counts + NN;
  int* srcidx = bsum + 256;
  float* Wc   = (float*)(srcidx + NT);
  int*  flag  = (int*)(Wc + 29344);

  const float* W1c  = Wc;
  const float* b1c  = Wc + 8192;
  const float* W2c  = Wc + 8256;
  const float* b2c  = Wc + 12352;
  const float* Wg1c = Wc + 12416;
  const float* as1c = Wc + 20608;
  const float* ad1c = Wc + 20736;
  const float* bg1c = Wc + 20864;
  const float* Wg2c = Wc + 20992;
  const float* as2c = Wc + 29184;
  const float* ad2c = Wc + 29248;
  const float* bg2c = Wc + 29312;

  auto nb = [](long long t){ return dim3((unsigned)((t + 255)/256)); };
  dim3 gnodes((NN + 3)/4);      // 4 waves/block, 1 wave per node

  // dtype detect + weight conversion
  k_detect<<<1, 256, 0, stream>>>(d_in[2], 8192, flag);
  SrcPtrs sp;
  for(int i = 0; i < 12; i++) sp.p[i] = d_in[2 + i];
  k_cvtall<<<12, 256, 0, stream>>>(sp, Wc, flag);

  // CSR build (shared by all 4 aggregations) — 3-phase parallel scan
  k_init_counts<<<nb(NN), 256, 0, stream>>>(counts);
  k_count_edges<<<nb(NE), 256, 0, stream>>>(ei, counts);
  k_scan1<<<NSCB, 256, 0, stream>>>(counts, bsum);
  k_scan2<<<1, 256, 0, stream>>>(bsum);
  k_scan3<<<NSCB, 256, 0, stream>>>(counts, bsum, rowptr, cursor, dinv, srcidx);
  k_fill<<<nb(NE), 256, 0, stream>>>(ei, cursor, srcidx);
  // after k_fill: cursor[n] == row end

  // ---- GCN1 ----  (GEMM prescales rows by dinv, writes bf16)
  k_gemm_in<128,64,true><<<dim3((NN+15)/16), 256, 0, stream>>>(x, W1c, dinv, Au, flag);
  k_gcn_gather<<<gnodes, 256, 0, stream>>>(rowptr, cursor, srcidx, dinv, Au32, b1c, B);

  // ---- GCN2 ----
  k_gemm_f<64,64,true><<<dim3((NN+15)/16), 256, 0, stream>>>(B, W2c, dinv, Au);
  k_gcn_gather<<<gnodes, 256, 0, stream>>>(rowptr, cursor, srcidx, dinv, Au32, b2c, B);

  // ---- GAT1: heads=2, C=64, concat ----
  k_gemm_f<64,128,false><<<dim3((NN+7)/8), 256, 0, stream>>>(B, Wg1c, dinv, Au);
  k_gat_scores<64><<<nb((long long)NN*2), 256, 0, stream>>>(Au32, as1c, ad1c, sS, sD);
  k_pack1<<<nb((long long)NN*64), 256, 0, stream>>>(Au, Ab);
  k_gat1_gather<<<gnodes, 256, 0, stream>>>(rowptr, cursor, srcidx, sS, sD, Ab, bg1c, B);

  // ---- GAT2: heads=2, C=32, mean + log_softmax ----
  k_gemm_f<128,64,false><<<dim3((NN+15)/16), 256, 0, stream>>>(B, Wg2c, dinv, Au);
  k_gat_scores<32><<<nb((long long)NN*2), 256, 0, stream>>>(Au32, as2c, ad2c, sS, sD);
  k_pack2<<<nb((long long)NN*32), 256, 0, stream>>>(Au, Ab);
  k_gat2_final<<<gnodes, 256, 0, stream>>>(rowptr, cursor, srcidx, sS, sD, Ab, bg2c, d_out, flag);
}

// Round 10
// 446.092 us; speedup vs baseline: 8.5329x; 1.0334x over previous
//
#include <hip/hip_runtime.h>
#include <hip/hip_bf16.h>

typedef __hip_bfloat16 bf16;

constexpr int NN = 50000;           // nodes
constexpr int NE = 800000;          // edges (without self loops)
constexpr int NT = NE + NN;         // edges incl self loops
constexpr int NSCB = (NN + 255)/256; // 196 scan blocks

// flag-selected load: f32 storage vs bf16 storage
__device__ __forceinline__ float cvt(const void* p, long long i, int f32){
  return f32 ? ((const float*)p)[i] : __bfloat162float(((const bf16*)p)[i]);
}
// bf16 <-> f32 (RNE pack)
__device__ __forceinline__ unsigned short f2bf(float f){
  unsigned u = __float_as_uint(f);
  u += 0x7fffu + ((u >> 16) & 1);
  return (unsigned short)(u >> 16);
}
__device__ __forceinline__ float bflo(unsigned p){ return __uint_as_float(p << 16); }
__device__ __forceinline__ float bfhi(unsigned p){ return __uint_as_float(p & 0xffff0000u); }
// monotone float<->uint key for atomicMax
__device__ __forceinline__ unsigned f2key(float f){
  unsigned u = __float_as_uint(f);
  return (u & 0x80000000u) ? ~u : (u | 0x80000000u);
}
__device__ __forceinline__ float key2f(unsigned k){
  unsigned u = (k & 0x80000000u) ? (k & 0x7fffffffu) : ~k;
  return __uint_as_float(u);
}

// Storage-dtype detector (see R2 notes): flag=1 => f32 storage, 0 => bf16.
__global__ void k_detect(const void* w, int n, int* flag){
  __shared__ int bad;
  if(threadIdx.x == 0) bad = 0;
  __syncthreads();
  const unsigned short* p = (const unsigned short*)w;
  int local = 0;
  for(int i = threadIdx.x; i < n; i += 256){
    int e = (p[i] >> 7) & 0xFF;
    if(e >= 0xC0) local = 1;
  }
  if(local) atomicOr(&bad, 1);
  __syncthreads();
  if(threadIdx.x == 0) *flag = bad;
}

struct SrcPtrs { const void* p[12]; };
__global__ void k_cvtall(SrcPtrs sp, float* Wc, const int* flag){
  const int sz[12]  = {8192,64,4096,64,8192,128,128,128,8192,64,64,32};
  const int off[12] = {0,8192,8256,12352,12416,20608,20736,20864,20992,29184,29248,29312};
  int b = blockIdx.x;
  int f = *flag;
  const void* src = sp.p[b];
  float* dst = Wc + off[b];
  int n = sz[b];
  for(int i = threadIdx.x; i < n; i += 256) dst[i] = cvt(src, i, f);
}

// ---------------- CSR build (dst-bucketed, self-loops included) ----------------
__global__ void k_init_counts(int* __restrict__ counts){
  int i = blockIdx.x*256 + threadIdx.x;
  if(i < NN) counts[i] = 1;          // self loop
}
__global__ void k_count_edges(const int* __restrict__ ei, int* __restrict__ counts){
  int e = blockIdx.x*256 + threadIdx.x;
  if(e < NE) atomicAdd(&counts[ei[NE + e]], 1);
}
__global__ void k_scan1(const int* __restrict__ counts, int* __restrict__ bsum){
  __shared__ int sh[256];
  int i = blockIdx.x*256 + threadIdx.x;
  sh[threadIdx.x] = (i < NN) ? counts[i] : 0;
  __syncthreads();
  for(int off = 128; off; off >>= 1){
    if(threadIdx.x < off) sh[threadIdx.x] += sh[threadIdx.x + off];
    __syncthreads();
  }
  if(threadIdx.x == 0) bsum[blockIdx.x] = sh[0];
}
__global__ void k_scan2(int* __restrict__ bsum){
  __shared__ int sh[2][256];
  int t = threadIdx.x;
  sh[0][t] = (t < NSCB) ? bsum[t] : 0;
  __syncthreads();
  int cur = 0;
  for(int off = 1; off < 256; off <<= 1){
    int nxt = cur^1;
    int v = sh[cur][t];
    if(t >= off) v += sh[cur][t-off];
    sh[nxt][t] = v;
    __syncthreads();
    cur = nxt;
  }
  if(t < NSCB) bsum[t] = (t == 0) ? 0 : sh[cur][t-1];
}
__global__ void k_scan3(const int* __restrict__ counts, const int* __restrict__ bsum,
                        int* __restrict__ rowptr, int* __restrict__ cursor,
                        float* __restrict__ dinv, int* __restrict__ srcidx){
  __shared__ int sh[2][256];
  int t = threadIdx.x;
  int i = blockIdx.x*256 + t;
  int c = (i < NN) ? counts[i] : 0;
  sh[0][t] = c;
  __syncthreads();
  int cur = 0;
  for(int off = 1; off < 256; off <<= 1){
    int nxt = cur^1;
    int v = sh[cur][t];
    if(t >= off) v += sh[cur][t-off];
    sh[nxt][t] = v;
    __syncthreads();
    cur = nxt;
  }
  if(i < NN){
    int excl = bsum[blockIdx.x] + sh[cur][t] - c;
    rowptr[i] = excl;
    srcidx[excl] = i;        // self-loop at row start, no atomic needed
    cursor[i] = excl + 1;    // edges fill after it
    dinv[i] = rsqrtf((float)c);
  }
}
__global__ void k_fill(const int* __restrict__ ei, int* __restrict__ cursor,
                       int* __restrict__ srcidx){
  int e = blockIdx.x*256 + threadIdx.x;
  if(e < NE){
    int dst = ei[NE + e];
    int pos = atomicAdd(&cursor[dst], 1);
    srcidx[pos] = ei[e];
  }
}
// after k_fill, cursor[n] == row end for node n.

// ---------------- dense layers (R8 structure, bf16 output) ----------------
template<int KIN, int KOUT, bool SCALE>
__global__ void k_gemm_f(const float* __restrict__ X, const float* __restrict__ W,
                         const float* __restrict__ dinv, unsigned short* __restrict__ Au){
  constexpr int TPR = KOUT/4;          // threads per row
  constexpr int R = 256/TPR;           // rows per block
  __shared__ float Wl[KIN*KOUT];
  __shared__ float Xl[R][KIN+4];
  int tid = threadIdx.x;
  for(int i = tid; i < KIN*KOUT/4; i += 256)
    ((float4*)Wl)[i] = ((const float4*)W)[i];
  int row0 = blockIdx.x*R;
  for(int i = tid; i < R*KIN/4; i += 256){
    int r = i/(KIN/4), k4 = i - r*(KIN/4);
    int rr = row0 + r;
    float4 v = (rr < NN) ? ((const float4*)(X + (size_t)rr*KIN))[k4]
                         : make_float4(0.f,0.f,0.f,0.f);
    *(float4*)&Xl[r][k4*4] = v;
  }
  __syncthreads();
  int ty = tid/TPR, tx = tid - ty*TPR;
  int row = row0 + ty;
  if(row >= NN) return;
  float a0=0.f, a1=0.f, a2=0.f, a3=0.f;
#pragma unroll
  for(int k = 0; k < KIN; k++){
    float xv = Xl[ty][k];
    float4 w = *(const float4*)&Wl[k*KOUT + tx*4];
    a0 += xv*w.x; a1 += xv*w.y; a2 += xv*w.z; a3 += xv*w.w;
  }
  float s = SCALE ? dinv[row] : 1.0f;
  ushort4 o;
  o.x = f2bf(a0*s); o.y = f2bf(a1*s); o.z = f2bf(a2*s); o.w = f2bf(a3*s);
  *(ushort4*)(Au + (size_t)row*KOUT + tx*4) = o;
}

template<int KIN, int KOUT, bool SCALE>
__global__ void k_gemm_in(const void* __restrict__ X, const float* __restrict__ W,
                          const float* __restrict__ dinv, unsigned short* __restrict__ Au,
                          const int* __restrict__ flag){
  constexpr int TPR = KOUT/4;
  constexpr int R = 256/TPR;
  __shared__ float Wl[KIN*KOUT];
  __shared__ float Xl[R][KIN+4];
  int tid = threadIdx.x;
  int f = *flag;
  for(int i = tid; i < KIN*KOUT/4; i += 256)
    ((float4*)Wl)[i] = ((const float4*)W)[i];
  int row0 = blockIdx.x*R;
  for(int i = tid; i < R*KIN; i += 256){
    int r = i/KIN, k = i - r*KIN;
    int rr = row0 + r;
    Xl[r][k] = (rr < NN) ? cvt(X, (long long)rr*KIN + k, f) : 0.0f;
  }
  __syncthreads();
  int ty = tid/TPR, tx = tid - ty*TPR;
  int row = row0 + ty;
  if(row >= NN) return;
  float a0=0.f, a1=0.f, a2=0.f, a3=0.f;
#pragma unroll
  for(int k = 0; k < KIN; k++){
    float xv = Xl[ty][k];
    float4 w = *(const float4*)&Wl[k*KOUT + tx*4];
    a0 += xv*w.x; a1 += xv*w.y; a2 += xv*w.z; a3 += xv*w.w;
  }
  float s = SCALE ? dinv[row] : 1.0f;
  ushort4 o;
  o.x = f2bf(a0*s); o.y = f2bf(a1*s); o.z = f2bf(a2*s); o.w = f2bf(a3*s);
  *(ushort4*)(Au + (size_t)row*KOUT + tx*4) = o;
}

// per (node, head) attention scores; also block-reduce global max of s -> SmaxKey[h]
template<int C>
__global__ void k_gat_scores(const unsigned* __restrict__ Au32, const float* __restrict__ asrc,
                             const float* __restrict__ adst, float* __restrict__ sS,
                             float* __restrict__ sD, unsigned* __restrict__ SmaxKey){
  __shared__ unsigned shm[256];
  int tid = threadIdx.x;
  int i = blockIdx.x*256 + tid;
  float s = 0.0f, d = 0.0f;
  if(i < NN*2){
    int node = i >> 1, h = i & 1;
    const unsigned* hp = Au32 + ((size_t)node*2*C + h*C)/2;
#pragma unroll
    for(int c = 0; c < C/2; c++){
      unsigned p = hp[c];
      float v0 = bflo(p), v1 = bfhi(p);
      s += v0*asrc[h*C + 2*c] + v1*asrc[h*C + 2*c + 1];
      d += v0*adst[h*C + 2*c] + v1*adst[h*C + 2*c + 1];
    }
    sS[i] = s; sD[i] = d;
    shm[tid] = f2key(s);
  } else shm[tid] = 0;   // key(<= -inf)
  __syncthreads();
  // parity-preserving max reduce (offsets all even): shm[0]=max h0, shm[1]=max h1
  for(int off = 128; off >= 2; off >>= 1){
    if(tid < off) shm[tid] = max(shm[tid], shm[tid + off]);
    __syncthreads();
  }
  if(tid < 2) atomicMax(&SmaxKey[tid], shm[tid]);
}

// head-interleave pack: Ab[n*64+c] = (bf16 h0[c]) | (bf16 h1[c] << 16)
__global__ void k_pack1(const unsigned short* __restrict__ Au, unsigned* __restrict__ Ab){
  int i = blockIdx.x*256 + threadIdx.x;
  if(i >= NN*64) return;
  int node = i >> 6, c = i & 63;
  unsigned lo = Au[(size_t)node*128 + c];
  unsigned hi = Au[(size_t)node*128 + 64 + c];
  Ab[i] = lo | (hi << 16);
}
__global__ void k_pack2(const unsigned short* __restrict__ Au, unsigned* __restrict__ Ab){
  int i = blockIdx.x*256 + threadIdx.x;
  if(i >= NN*32) return;
  int node = i >> 5, c = i & 31;
  unsigned lo = Au[(size_t)node*64 + c];
  unsigned hi = Au[(size_t)node*64 + 32 + c];
  Ab[i] = lo | (hi << 16);
}

// ---------------- gather aggregations (one wave per dst node) ----------------
// GCN: 8 lanes/edge, 8 edges/iter; row = 64 bf16 = 8 uint4 slots.
__global__ void k_gcn_gather(const int* __restrict__ rowptr, const int* __restrict__ rowend,
                             const int* __restrict__ srcidx, const float* __restrict__ dinv,
                             const unsigned* __restrict__ Au32, const float* __restrict__ bias,
                             float* __restrict__ B){
  int wid = threadIdx.x >> 6, lane = threadIdx.x & 63;
  int n = blockIdx.x*4 + wid;
  if(n >= NN) return;
  int s0 = rowptr[n], ne = rowend[n] - s0;
  int o = lane >> 3, c4 = lane & 7;
  float a0=0,a1=0,a2=0,a3=0,a4=0,a5=0,a6=0,a7=0;
  for(int base = 0; base < ne; base += 64){
    int my = base + lane;
    int src = (my < ne) ? srcidx[s0 + my] : -1;
    int cnt = min(64, ne - base);
    int iters = (cnt + 7) >> 3;
#pragma unroll 4
    for(int j = 0; j < iters; j++){
      int sb = __shfl(src, 8*j + o);
      if(sb >= 0){
        uint4 p = *(const uint4*)(Au32 + (size_t)sb*32 + c4*4);
        a0 += bflo(p.x); a1 += bfhi(p.x);
        a2 += bflo(p.y); a3 += bfhi(p.y);
        a4 += bflo(p.z); a5 += bfhi(p.z);
        a6 += bflo(p.w); a7 += bfhi(p.w);
      }
    }
  }
#pragma unroll
  for(int off = 8; off <= 32; off <<= 1){
    a0 += __shfl_xor(a0, off); a1 += __shfl_xor(a1, off);
    a2 += __shfl_xor(a2, off); a3 += __shfl_xor(a3, off);
    a4 += __shfl_xor(a4, off); a5 += __shfl_xor(a5, off);
    a6 += __shfl_xor(a6, off); a7 += __shfl_xor(a7, off);
  }
  if(o == 0){
    float dn = dinv[n];
    int cb = 8*c4;
    float4 v0, v1;
    v0.x = fmaxf(a0*dn + bias[cb+0], 0.0f);
    v0.y = fmaxf(a1*dn + bias[cb+1], 0.0f);
    v0.z = fmaxf(a2*dn + bias[cb+2], 0.0f);
    v0.w = fmaxf(a3*dn + bias[cb+3], 0.0f);
    v1.x = fmaxf(a4*dn + bias[cb+4], 0.0f);
    v1.y = fmaxf(a5*dn + bias[cb+5], 0.0f);
    v1.z = fmaxf(a6*dn + bias[cb+6], 0.0f);
    v1.w = fmaxf(a7*dn + bias[cb+7], 0.0f);
    *(float4*)(B + (size_t)n*64 + cb)     = v0;
    *(float4*)(B + (size_t)n*64 + cb + 4) = v1;
  }
}

// GAT1 (heads=2, C=64, concat): SINGLE-PASS softmax via global-bound m̂;
// 16 lanes/edge, 4 edges/iter; row = 64 dwords = 16 uint4 slots.
__global__ void k_gat1_gather(const int* __restrict__ rowptr, const int* __restrict__ rowend,
                              const int* __restrict__ srcidx, const float* __restrict__ sS,
                              const float* __restrict__ sD, const unsigned* __restrict__ Ab,
                              const float* __restrict__ bias, float* __restrict__ B,
                              const unsigned* __restrict__ SmaxKey){
  int wid = threadIdx.x >> 6, lane = threadIdx.x & 63;
  int n = blockIdx.x*4 + wid;
  if(n >= NN) return;
  int s0 = rowptr[n], ne = rowend[n] - s0;
  float d0 = sD[n*2], d1 = sD[n*2+1];
  float t0 = key2f(SmaxKey[0]) + d0;  float m0 = t0 > 0.0f ? t0 : 0.2f*t0;
  float t1 = key2f(SmaxKey[1]) + d1;  float m1 = t1 > 0.0f ? t1 : 0.2f*t1;
  int q = lane >> 4, c4 = lane & 15;
  float z0 = 0.0f, z1 = 0.0f;
  float b0=0,b1=0,b2=0,b3=0, c0=0,c1=0,c2=0,c3=0;
  for(int base = 0; base < ne; base += 64){
    int my = base + lane;
    int src = 0; float w0 = 0.0f, w1 = 0.0f;
    if(my < ne){
      src = srcidx[s0 + my];
      float2 sv = *(const float2*)(sS + src*2);
      float e0 = sv.x + d0; e0 = e0 > 0.0f ? e0 : 0.2f*e0;
      float e1 = sv.y + d1; e1 = e1 > 0.0f ? e1 : 0.2f*e1;
      w0 = __expf(e0 - m0); w1 = __expf(e1 - m1);
      z0 += w0; z1 += w1;
    }
    int cnt = min(64, ne - base);
    int iters = (cnt + 3) >> 2;
#pragma unroll 4
    for(int j = 0; j < iters; j++){
      int idx = 4*j + q;
      int sb = __shfl(src, idx);
      float a0 = __shfl(w0, idx), a1 = __shfl(w1, idx);
      uint4 p = *(const uint4*)(Ab + (size_t)sb*64 + c4*4);
      b0 += bflo(p.x)*a0; c0 += bfhi(p.x)*a1;
      b1 += bflo(p.y)*a0; c1 += bfhi(p.y)*a1;
      b2 += bflo(p.z)*a0; c2 += bfhi(p.z)*a1;
      b3 += bflo(p.w)*a0; c3 += bfhi(p.w)*a1;
    }
  }
#pragma unroll
  for(int off = 1; off <= 32; off <<= 1){ z0 += __shfl_xor(z0, off); z1 += __shfl_xor(z1, off); }
#pragma unroll
  for(int off = 16; off <= 32; off <<= 1){
    b0 += __shfl_xor(b0, off); b1 += __shfl_xor(b1, off);
    b2 += __shfl_xor(b2, off); b3 += __shfl_xor(b3, off);
    c0 += __shfl_xor(c0, off); c1 += __shfl_xor(c1, off);
    c2 += __shfl_xor(c2, off); c3 += __shfl_xor(c3, off);
  }
  if(q == 0){
    float iz0 = 1.0f/(z0 + 1e-16f), iz1 = 1.0f/(z1 + 1e-16f);
    int cb = 4*c4;
    float4 o0, o1;
    o0.x = fmaxf(b0*iz0 + bias[cb+0], 0.0f);
    o0.y = fmaxf(b1*iz0 + bias[cb+1], 0.0f);
    o0.z = fmaxf(b2*iz0 + bias[cb+2], 0.0f);
    o0.w = fmaxf(b3*iz0 + bias[cb+3], 0.0f);
    o1.x = fmaxf(c0*iz1 + bias[64+cb+0], 0.0f);
    o1.y = fmaxf(c1*iz1 + bias[64+cb+1], 0.0f);
    o1.z = fmaxf(c2*iz1 + bias[64+cb+2], 0.0f);
    o1.w = fmaxf(c3*iz1 + bias[64+cb+3], 0.0f);
    *(float4*)(B + (size_t)n*128 + cb)      = o0;
    *(float4*)(B + (size_t)n*128 + 64 + cb) = o1;
  }
}

// GAT2 (heads=2, C=32, mean) + bias + log_softmax, single-pass softmax;
// 8 lanes/edge, 8 edges/iter; row = 32 dwords = 8 uint4 slots.
__global__ void k_gat2_final(const int* __restrict__ rowptr, const int* __restrict__ rowend,
                             const int* __restrict__ srcidx, const float* __restrict__ sS,
                             const float* __restrict__ sD, const unsigned* __restrict__ Ab,
                             const float* __restrict__ bias, void* __restrict__ out,
                             const int* __restrict__ flag, const unsigned* __restrict__ SmaxKey){
  int wid = threadIdx.x >> 6, lane = threadIdx.x & 63;
  int n = blockIdx.x*4 + wid;
  if(n >= NN) return;
  int s0 = rowptr[n], ne = rowend[n] - s0;
  float d0 = sD[n*2], d1 = sD[n*2+1];
  float t0 = key2f(SmaxKey[0]) + d0;  float m0 = t0 > 0.0f ? t0 : 0.2f*t0;
  float t1 = key2f(SmaxKey[1]) + d1;  float m1 = t1 > 0.0f ? t1 : 0.2f*t1;
  int o = lane >> 3, c4 = lane & 7;
  float z0 = 0.0f, z1 = 0.0f;
  float b0=0,b1=0,b2=0,b3=0, c0=0,c1=0,c2=0,c3=0;
  for(int base = 0; base < ne; base += 64){
    int my = base + lane;
    int src = 0; float w0 = 0.0f, w1 = 0.0f;
    if(my < ne){
      src = srcidx[s0 + my];
      float2 sv = *(const float2*)(sS + src*2);
      float e0 = sv.x + d0; e0 = e0 > 0.0f ? e0 : 0.2f*e0;
      float e1 = sv.y + d1; e1 = e1 > 0.0f ? e1 : 0.2f*e1;
      w0 = __expf(e0 - m0); w1 = __expf(e1 - m1);
      z0 += w0; z1 += w1;
    }
    int cnt = min(64, ne - base);
    int iters = (cnt + 7) >> 3;
#pragma unroll 4
    for(int j = 0; j < iters; j++){
      int idx = 8*j + o;
      int sb = __shfl(src, idx);
      float a0 = __shfl(w0, idx), a1 = __shfl(w1, idx);
      uint4 p = *(const uint4*)(Ab + (size_t)sb*32 + c4*4);
      b0 += bflo(p.x)*a0; c0 += bfhi(p.x)*a1;
      b1 += bflo(p.y)*a0; c1 += bfhi(p.y)*a1;
      b2 += bflo(p.z)*a0; c2 += bfhi(p.z)*a1;
      b3 += bflo(p.w)*a0; c3 += bfhi(p.w)*a1;
    }
  }
#pragma unroll
  for(int off = 1; off <= 32; off <<= 1){ z0 += __shfl_xor(z0, off); z1 += __shfl_xor(z1, off); }
#pragma unroll
  for(int off = 8; off <= 32; off <<= 1){
    b0 += __shfl_xor(b0, off); b1 += __shfl_xor(b1, off);
    b2 += __shfl_xor(b2, off); b3 += __shfl_xor(b3, off);
    c0 += __shfl_xor(c0, off); c1 += __shfl_xor(c1, off);
    c2 += __shfl_xor(c2, off); c3 += __shfl_xor(c3, off);
  }
  // all lanes now hold totals for their c4; lanes with o==0 will store
  float iz0 = 1.0f/(z0 + 1e-16f), iz1 = 1.0f/(z1 + 1e-16f);
  int cb = 4*c4;
  float o0 = 0.5f*(b0*iz0 + c0*iz1) + bias[cb+0];
  float o1 = 0.5f*(b1*iz0 + c1*iz1) + bias[cb+1];
  float o2 = 0.5f*(b2*iz0 + c2*iz1) + bias[cb+2];
  float o3 = 0.5f*(b3*iz0 + c3*iz1) + bias[cb+3];
  // log_softmax over 32 channels: 8 lanes x 4 values (butterfly stays in octet)
  float mx = fmaxf(fmaxf(o0, o1), fmaxf(o2, o3));
  for(int off = 4; off; off >>= 1) mx = fmaxf(mx, __shfl_xor(mx, off));
  float sm = __expf(o0 - mx) + __expf(o1 - mx) + __expf(o2 - mx) + __expf(o3 - mx);
  for(int off = 4; off; off >>= 1) sm += __shfl_xor(sm, off);
  float lse = mx + __logf(sm);
  if(o == 0){
    if(*flag){
      float4 r;
      r.x = o0 - lse; r.y = o1 - lse; r.z = o2 - lse; r.w = o3 - lse;
      *(float4*)((float*)out + (size_t)n*32 + cb) = r;
    } else {
      uint2 r;
      r.x = (unsigned)f2bf(o0 - lse) | ((unsigned)f2bf(o1 - lse) << 16);
      r.y = (unsigned)f2bf(o2 - lse) | ((unsigned)f2bf(o3 - lse) << 16);
      *(uint2*)((unsigned*)out + (size_t)n*16 + 2*c4) = r;
    }
  }
}

extern "C" void kernel_launch(void* const* d_in, const int* in_sizes, int n_in,
                              void* d_out, int out_size, void* d_ws, size_t ws_size,
                              hipStream_t stream) {
  const void* x   = d_in[0];
  const int*  ei  = (const int*)d_in[1];

  // workspace layout:
  // A-region 25.6MB: Au bf16 [<=NN*128] | Ab u32 [<=NN*64] (at +12.8MB)
  // then B[NN*128] f32 | dinv | sS | sD | rowptr | cursor | counts | bsum | srcidx | Wc | flag | SmaxKey[2]
  float* A    = (float*)d_ws;
  unsigned short* Au = (unsigned short*)A;
  unsigned* Au32 = (unsigned*)A;
  unsigned* Ab = (unsigned*)(A + (size_t)NN*64);   // +12.8MB
  float* B    = A + (size_t)NN*128;
  float* dinv = B + (size_t)NN*128;
  float* sS   = dinv + NN;
  float* sD   = sS + 2*NN;
  int* rowptr = (int*)(sD + 2*NN);
  int* cursor = rowptr + NN;
  int* counts = cursor + NN;
  int* bsum   = counts + NN;
  int* srcidx = bsum + 256;
  float* Wc   = (float*)(srcidx + NT);
  int*  flag  = (int*)(Wc + 29344);
  unsigned* SmaxKey = (unsigned*)(flag + 1);

  const float* W1c  = Wc;
  const float* b1c  = Wc + 8192;
  const float* W2c  = Wc + 8256;
  const float* b2c  = Wc + 12352;
  const float* Wg1c = Wc + 12416;
  const float* as1c = Wc + 20608;
  const float* ad1c = Wc + 20736;
  const float* bg1c = Wc + 20864;
  const float* Wg2c = Wc + 20992;
  const float* as2c = Wc + 29184;
  const float* ad2c = Wc + 29248;
  const float* bg2c = Wc + 29312;

  auto nb = [](long long t){ return dim3((unsigned)((t + 255)/256)); };
  dim3 gnodes((NN + 3)/4);      // 4 waves/block, 1 wave per node

  // dtype detect + weight conversion
  k_detect<<<1, 256, 0, stream>>>(d_in[2], 8192, flag);
  SrcPtrs sp;
  for(int i = 0; i < 12; i++) sp.p[i] = d_in[2 + i];
  k_cvtall<<<12, 256, 0, stream>>>(sp, Wc, flag);

  // CSR build (shared by all 4 aggregations) — 3-phase parallel scan
  k_init_counts<<<nb(NN), 256, 0, stream>>>(counts);
  k_count_edges<<<nb(NE), 256, 0, stream>>>(ei, counts);
  k_scan1<<<NSCB, 256, 0, stream>>>(counts, bsum);
  k_scan2<<<1, 256, 0, stream>>>(bsum);
  k_scan3<<<NSCB, 256, 0, stream>>>(counts, bsum, rowptr, cursor, dinv, srcidx);
  k_fill<<<nb(NE), 256, 0, stream>>>(ei, cursor, srcidx);
  // after k_fill: cursor[n] == row end

  // ---- GCN1 ----  (GEMM prescales rows by dinv, writes bf16)
  k_gemm_in<128,64,true><<<dim3((NN+15)/16), 256, 0, stream>>>(x, W1c, dinv, Au, flag);
  k_gcn_gather<<<gnodes, 256, 0, stream>>>(rowptr, cursor, srcidx, dinv, Au32, b1c, B);

  // ---- GCN2 ----
  k_gemm_f<64,64,true><<<dim3((NN+15)/16), 256, 0, stream>>>(B, W2c, dinv, Au);
  k_gcn_gather<<<gnodes, 256, 0, stream>>>(rowptr, cursor, srcidx, dinv, Au32, b2c, B);

  // ---- GAT1: heads=2, C=64, concat ----
  k_gemm_f<64,128,false><<<dim3((NN+7)/8), 256, 0, stream>>>(B, Wg1c, dinv, Au);
  hipMemsetAsync(SmaxKey, 0, 8, stream);
  k_gat_scores<64><<<nb((long long)NN*2), 256, 0, stream>>>(Au32, as1c, ad1c, sS, sD, SmaxKey);
  k_pack1<<<nb((long long)NN*64), 256, 0, stream>>>(Au, Ab);
  k_gat1_gather<<<gnodes, 256, 0, stream>>>(rowptr, cursor, srcidx, sS, sD, Ab, bg1c, B, SmaxKey);

  // ---- GAT2: heads=2, C=32, mean + log_softmax ----
  k_gemm_f<128,64,false><<<dim3((NN+15)/16), 256, 0, stream>>>(B, Wg2c, dinv, Au);
  hipMemsetAsync(SmaxKey, 0, 8, stream);
  k_gat_scores<32><<<nb((long long)NN*2), 256, 0, stream>>>(Au32, as2c, ad2c, sS, sD, SmaxKey);
  k_pack2<<<nb((long long)NN*32), 256, 0, stream>>>(Au, Ab);
  k_gat2_final<<<gnodes, 256, 0, stream>>>(rowptr, cursor, srcidx, sS, sD, Ab, bg2c, d_out, flag, SmaxKey);
}